// Round 1
// baseline (2465.455 us; speedup 1.0000x reference)
//
#include <hip/hip_runtime.h>
#include <math.h>

// B=512 S=64 D=128 V=256 NH=4 HD=32 INNER=256 NHM=4 DHM=64 BS=4 NB=64 K=4 FF=128

__device__ __forceinline__ float sigf(float x){ return 1.f/(1.f+__expf(-x)); }
__device__ __forceinline__ float siluf(float x){ return x/(1.f+__expf(-x)); }
__device__ __forceinline__ float logsigf(float x){ return fminf(x,0.f) - log1pf(__expf(-fabsf(x))); }
__device__ __forceinline__ float geluf(float x){
  return 0.5f*x*(1.f+tanhf(0.7978845608028654f*(x+0.044715f*x*x*x)));
}
__device__ __forceinline__ void sums4(float4 v, float& s, float& q){
  s += v.x+v.y+v.z+v.w;
  q += v.x*v.x+v.y*v.y+v.z*v.z+v.w*v.w;
}

// LayerNorm rows of 128; 8 threads per row; dst[r*dstride+c] = (x-mu)*rsqrt(var+eps)*w[c]
__device__ __forceinline__ void ln_rows(const float* __restrict__ src, const float* __restrict__ lnw,
                                        float* __restrict__ dst, int dstride,
                                        float (*red)[8], float (*red2)[8], int t)
{
  int r = t >> 3, l8 = t & 7;
  const float4* s4 = (const float4*)(src + (size_t)r*128 + l8*16);
  float4 v0=s4[0], v1=s4[1], v2=s4[2], v3=s4[3];
  float su=0.f, sq=0.f;
  sums4(v0,su,sq); sums4(v1,su,sq); sums4(v2,su,sq); sums4(v3,su,sq);
  red[r][l8]=su; red2[r][l8]=sq;
  __syncthreads();
  float ts=0.f, tq=0.f;
  #pragma unroll
  for (int k=0;k<8;k++){ ts+=red[r][k]; tq+=red2[r][k]; }
  float mu = ts*(1.f/128.f);
  float var = tq*(1.f/128.f) - mu*mu;
  float iv = rsqrtf(var+1e-5f);
  int c0 = l8*16;
  float vv[16];
  *(float4*)&vv[0]=v0; *(float4*)&vv[4]=v1; *(float4*)&vv[8]=v2; *(float4*)&vv[12]=v3;
  #pragma unroll
  for (int q2=0;q2<16;q2++) dst[r*dstride + c0 + q2] = (vv[q2]-mu)*iv*lnw[c0+q2];
}

// ---------------- embed ----------------
__global__ __launch_bounds__(256) void k_embed(const int* __restrict__ x, const float* __restrict__ embed,
                                               float* __restrict__ h)
{
  int idx4 = blockIdx.x*256 + threadIdx.x;      // over B*S*D/4 = 1048576 float4
  int tok = idx4 >> 5;
  int c4  = idx4 & 31;
  int id = x[tok];
  reinterpret_cast<float4*>(h)[idx4] = reinterpret_cast<const float4*>(embed)[id*32 + c4];
}

// ---------------- sLSTM (fused LN + scan + head-LN + residual) ----------------
__global__ __launch_bounds__(512) void k_slstm(
    float* __restrict__ h, const float* __restrict__ lnw,
    const float* __restrict__ gw, const float* __restrict__ rw,
    const float* __restrict__ bias, const float* __restrict__ gn)
{
  __shared__ float xh[64][128];     // LN-ed input, overwritten per-step with y
  __shared__ float hb[128];
  __shared__ float raw[512];
  __shared__ float red[64][8];
  __shared__ float red2[64][8];
  __shared__ float mu_s[64][4];
  __shared__ float iv_s[64][4];

  int t = threadIdx.x;
  int b = blockIdx.x;
  float* hrow = h + (size_t)b*8192;

  ln_rows(hrow, lnw, &xh[0][0], 128, red, red2, t);
  __syncthreads();

  int g  = t >> 7;
  int nh = (t >> 5) & 3;
  int e  = t & 31;
  float wg[32], wr[32];
  {
    const float4* g4 = (const float4*)(gw + (((g*4+nh)*32+e)*32));
    const float4* r4 = (const float4*)(rw + (((g*4+nh)*32+e)*32));
    #pragma unroll
    for (int q=0;q<8;q++){
      float4 a=g4[q]; wg[4*q]=a.x; wg[4*q+1]=a.y; wg[4*q+2]=a.z; wg[4*q+3]=a.w;
      float4 c=r4[q]; wr[4*q]=c.x; wr[4*q+1]=c.y; wr[4*q+2]=c.z; wr[4*q+3]=c.w;
    }
  }
  float bs = bias[(g*4+nh)*32+e];
  float c_s=0.f, n_s=0.f, m_s=0.f;
  if (t<128) hb[t]=0.f;
  __syncthreads();

  for (int s=0;s<64;s++){
    const float4* xr = (const float4*)&xh[s][nh*32];
    const float4* hr = (const float4*)&hb[nh*32];
    float acc = bs;
    #pragma unroll
    for (int q=0;q<8;q++){
      float4 xv = xr[q]; float4 hv = hr[q];
      acc += xv.x*wg[4*q+0] + xv.y*wg[4*q+1] + xv.z*wg[4*q+2] + xv.w*wg[4*q+3];
      acc += hv.x*wr[4*q+0] + hv.y*wr[4*q+1] + hv.z*wr[4*q+2] + hv.w*wr[4*q+3];
    }
    raw[t] = acc;
    __syncthreads();
    if (t < 128){
      float i_r = raw[t], f_r = raw[128+t], z_r = raw[256+t], o_r = raw[384+t];
      float lf = m_s + logsigf(f_r);
      float mn = fmaxf(i_r, lf);
      float iv = __expf(i_r-mn), fv = __expf(lf-mn);
      c_s = fv*c_s + iv*tanhf(z_r);
      n_s = fv*n_s + iv;
      m_s = mn;
      float hn = sigf(o_r)*c_s/n_s;
      hb[t] = hn;
      xh[s][t] = hn;
    }
    __syncthreads();
  }

  if (t < 256){
    int s = t>>2, n = t&3;
    const float4* yr = (const float4*)&xh[s][n*32];
    float su=0.f, sq=0.f;
    #pragma unroll
    for (int q=0;q<8;q++){ float4 v = yr[q]; sums4(v,su,sq); }
    float mu = su*(1.f/32.f);
    float var = sq*(1.f/32.f) - mu*mu;
    mu_s[s][n]=mu; iv_s[s][n]=rsqrtf(var+1e-5f);
  }
  __syncthreads();
  #pragma unroll
  for (int rr=0; rr<16; rr++){
    int idx = t + 512*rr;
    int s = idx>>7, c = idx&127;
    float y = (xh[s][c] - mu_s[s][c>>5]) * iv_s[s][c>>5] * gn[c];
    hrow[idx] += y;
  }
}

// ---------------- FFN (fused LN + up/gelu-gate + down + residual) ----------------
__global__ __launch_bounds__(256) void k_ffn(
    float* __restrict__ h, const float* __restrict__ lnw,
    const float* __restrict__ up, const float* __restrict__ down)
{
  __shared__ float xln[32][132];
  __shared__ float hid[32][132];
  __shared__ float red[32][8];
  __shared__ float red2[32][8];
  int t = threadIdx.x;
  size_t tok0 = (size_t)blockIdx.x * 32;

  ln_rows(h + tok0*128, lnw, &xln[0][0], 132, red, red2, t);
  __syncthreads();

  int tm = t>>4, om = t&15;
  int o0 = om*8, r0 = tm*2;
  float accg[2][8], accu[2][8];
  #pragma unroll
  for (int j=0;j<8;j++){ accg[0][j]=0.f; accg[1][j]=0.f; accu[0][j]=0.f; accu[1][j]=0.f; }
  for (int k=0;k<128;k++){
    float x0 = xln[r0][k], x1 = xln[r0+1][k];
    const float4* w1 = (const float4*)(up + (size_t)k*256 + o0);
    const float4* w2 = (const float4*)(up + (size_t)k*256 + 128 + o0);
    float wgv[8], wuv[8];
    *(float4*)&wgv[0]=w1[0]; *(float4*)&wgv[4]=w1[1];
    *(float4*)&wuv[0]=w2[0]; *(float4*)&wuv[4]=w2[1];
    #pragma unroll
    for (int j=0;j<8;j++){
      accg[0][j]+=x0*wgv[j]; accg[1][j]+=x1*wgv[j];
      accu[0][j]+=x0*wuv[j]; accu[1][j]+=x1*wuv[j];
    }
  }
  #pragma unroll
  for (int tt=0;tt<2;tt++)
    #pragma unroll
    for (int j=0;j<8;j++)
      hid[r0+tt][o0+j] = geluf(accg[tt][j]) * accu[tt][j];
  __syncthreads();

  float acc[2][8];
  #pragma unroll
  for (int j=0;j<8;j++){ acc[0][j]=0.f; acc[1][j]=0.f; }
  for (int k=0;k<128;k++){
    float x0 = hid[r0][k], x1 = hid[r0+1][k];
    const float4* w1 = (const float4*)(down + (size_t)k*128 + o0);
    float wv[8];
    *(float4*)&wv[0]=w1[0]; *(float4*)&wv[4]=w1[1];
    #pragma unroll
    for (int j=0;j<8;j++){ acc[0][j]+=x0*wv[j]; acc[1][j]+=x1*wv[j]; }
  }
  #pragma unroll
  for (int tt=0;tt<2;tt++){
    float* dst = h + (tok0 + r0 + tt)*128 + o0;
    float4 h0 = ((float4*)dst)[0], h1 = ((float4*)dst)[1];
    h0.x += acc[tt][0]; h0.y += acc[tt][1]; h0.z += acc[tt][2]; h0.w += acc[tt][3];
    h1.x += acc[tt][4]; h1.y += acc[tt][5]; h1.z += acc[tt][6]; h1.w += acc[tt][7];
    ((float4*)dst)[0]=h0; ((float4*)dst)[1]=h1;
  }
}

// ---------------- mLSTM up-projection (LN + 128->512, writes xm and z) ----------------
__global__ __launch_bounds__(256) void k_up(
    const float* __restrict__ h, const float* __restrict__ lnw,
    const float* __restrict__ up, float* __restrict__ xm, float* __restrict__ z)
{
  __shared__ float xln[32][132];
  __shared__ float red[32][8];
  __shared__ float red2[32][8];
  int t = threadIdx.x;
  size_t tok0 = (size_t)blockIdx.x * 32;

  ln_rows(h + tok0*128, lnw, &xln[0][0], 132, red, red2, t);
  __syncthreads();

  int tm = t>>4, om = t&15;
  int o0 = om*32, r0 = tm*2;
  float acc[2][32];
  #pragma unroll
  for (int j=0;j<32;j++){ acc[0][j]=0.f; acc[1][j]=0.f; }
  for (int k=0;k<128;k++){
    float x0 = xln[r0][k], x1 = xln[r0+1][k];
    const float4* wrow = (const float4*)(up + (size_t)k*512 + o0);
    #pragma unroll
    for (int q=0;q<8;q++){
      float4 w = wrow[q];
      acc[0][q*4+0]+=x0*w.x; acc[0][q*4+1]+=x0*w.y; acc[0][q*4+2]+=x0*w.z; acc[0][q*4+3]+=x0*w.w;
      acc[1][q*4+0]+=x1*w.x; acc[1][q*4+1]+=x1*w.y; acc[1][q*4+2]+=x1*w.z; acc[1][q*4+3]+=x1*w.w;
    }
  }
  #pragma unroll
  for (int tt=0;tt<2;tt++){
    float* dst = (o0 < 256) ? (xm + (tok0 + r0 + tt)*256 + o0)
                            : (z  + (tok0 + r0 + tt)*256 + (o0-256));
    #pragma unroll
    for (int q=0;q<8;q++){
      float4 w;
      w.x = acc[tt][q*4+0]; w.y = acc[tt][q*4+1]; w.z = acc[tt][q*4+2]; w.w = acc[tt][q*4+3];
      ((float4*)dst)[q] = w;
    }
  }
}

// ---------------- mLSTM conv + silu + gate projections ----------------
__global__ __launch_bounds__(256) void k_convgates(
    const float* __restrict__ xm, float* __restrict__ xc,
    const float* __restrict__ cw, const float* __restrict__ cb,
    const float* __restrict__ qkvw,
    const float* __restrict__ igw, const float* __restrict__ igb,
    const float* __restrict__ fgw, const float* __restrict__ fgb,
    float* __restrict__ ig, float* __restrict__ fg)
{
  __shared__ float xms[64][260];
  __shared__ float xcs[64][260];
  __shared__ float cwl[1024];
  __shared__ float cbl[256];
  int t = threadIdx.x;
  int b = blockIdx.x;
  const float* src = xm + (size_t)b*16384;

  #pragma unroll
  for (int j=0;j<16;j++){
    int f4 = t + 256*j;
    int r = f4 >> 6, c4 = f4 & 63;
    *(float4*)&xms[r][c4*4] = ((const float4*)src)[f4];
  }
  *(float4*)&cwl[t*4] = ((const float4*)cw)[t];       // 256 channels x 4 taps
  if (t < 64) *(float4*)&cbl[t*4] = ((const float4*)cb)[t];
  __syncthreads();

  int c4 = t & 63; int c0 = c4*4;
  int sr = t >> 6;
  float4 wk[4];
  #pragma unroll
  for (int k=0;k<4;k++)
    wk[k] = make_float4(cwl[(c0+0)*4+k], cwl[(c0+1)*4+k], cwl[(c0+2)*4+k], cwl[(c0+3)*4+k]);
  float4 bias4 = *(float4*)&cbl[c0];
  for (int j=0;j<16;j++){
    int s = sr*16 + j;
    float4 a = bias4;
    #pragma unroll
    for (int k=0;k<4;k++){
      int sp = s - 3 + k;
      if (sp >= 0){
        float4 xv = *(const float4*)&xms[sp][c0];
        a.x += xv.x*wk[k].x; a.y += xv.y*wk[k].y; a.z += xv.z*wk[k].z; a.w += xv.w*wk[k].w;
      }
    }
    a.x = siluf(a.x); a.y = siluf(a.y); a.z = siluf(a.z); a.w = siluf(a.w);
    *(float4*)&xcs[s][c0] = a;
    *(float4*)(xc + (size_t)b*16384 + (size_t)s*256 + c0) = a;
  }
  __syncthreads();

  int s = t >> 2, p = t & 3;
  float gig[4] = {0.f,0.f,0.f,0.f}, gfg[4] = {0.f,0.f,0.f,0.f};
  for (int gi = p*192; gi < p*192+192; gi++){
    int which = gi >> 8;
    int idx = gi & 255;
    int nb = idx >> 2, o = idx & 3;
    float4 w = *(const float4*)(qkvw + which*1024 + nb*16 + o*4);
    const float* s2 = (which==2) ? &xms[s][nb*4] : &xcs[s][nb*4];
    float val = w.x*s2[0] + w.y*s2[1] + w.z*s2[2] + w.w*s2[3];
    float4 gw4 = *(const float4*)(igw + (size_t)gi*4);
    float4 fw4 = *(const float4*)(fgw + (size_t)gi*4);
    gig[0]+=val*gw4.x; gig[1]+=val*gw4.y; gig[2]+=val*gw4.z; gig[3]+=val*gw4.w;
    gfg[0]+=val*fw4.x; gfg[1]+=val*fw4.y; gfg[2]+=val*fw4.z; gfg[3]+=val*fw4.w;
  }
  #pragma unroll
  for (int m=0;m<4;m++){
    gig[m] += __shfl_xor(gig[m],1,4); gig[m] += __shfl_xor(gig[m],2,4);
    gfg[m] += __shfl_xor(gfg[m],1,4); gfg[m] += __shfl_xor(gfg[m],2,4);
  }
  if (p == 0){
    #pragma unroll
    for (int m=0;m<4;m++){
      ig[(size_t)b*256 + m*64 + s] = gig[m] + igb[m];
      fg[(size_t)b*256 + m*64 + s] = gfg[m] + fgb[m];
    }
  }
}

// ---------------- mLSTM attention per (b, head); writes head-LN'ed h into xm buffer ----------------
__global__ __launch_bounds__(256) void k_attn(
    float* __restrict__ xm, const float* __restrict__ xc,
    const float* __restrict__ qkvw,
    const float* __restrict__ igp, const float* __restrict__ fgp,
    const float* __restrict__ onorm)
{
  __shared__ float qs[64][68];
  __shared__ float ksm[64][68];
  __shared__ float vsm[64][68];
  __shared__ float xcl[64][68];
  __shared__ float xml[64][68];
  __shared__ float cnm[64][65];
  __shared__ float csum[65];
  __shared__ float pmax[64];
  __shared__ float igl[64];
  __shared__ float lfs[64];
  __shared__ float nrec[64];

  int t = threadIdx.x;
  int b = blockIdx.x >> 2, hh = blockIdx.x & 3;
  const float* xcb = xc + (size_t)b*16384 + hh*64;
  float* xmb = xm + (size_t)b*16384 + hh*64;

  #pragma unroll
  for (int j=0;j<4;j++){
    int u = t + 256*j;
    int r = u >> 4, q4 = u & 15;
    *(float4*)&xcl[r][q4*4] = *(const float4*)(xcb + (size_t)r*256 + q4*4);
    *(float4*)&xml[r][q4*4] = *(const float4*)(xmb + (size_t)r*256 + q4*4);
  }
  if (t < 64){
    lfs[t] = logsigf(fgp[(size_t)b*256 + hh*64 + t]);
    igl[t] = igp[(size_t)b*256 + hh*64 + t];
  }
  __syncthreads();
  if (t == 0){
    float cacc = 0.f, pm = -1e30f;
    csum[0] = 0.f;
    for (int s=0;s<64;s++){
      cacc += lfs[s];
      csum[s+1] = cacc;
      pm = fmaxf(pm, igl[s] - cacc);
      pmax[s] = pm;
    }
  }
  #pragma unroll
  for (int j=0;j<4;j++){
    int u = t + 256*j;
    int s = u >> 4, lb = u & 15;
    int nb = hh*16 + lb;
    const float* xq = &xcl[s][lb*4];
    const float* xv = &xml[s][lb*4];
    #pragma unroll
    for (int o=0;o<4;o++){
      float4 wq = *(const float4*)(qkvw + nb*16 + o*4);
      float4 wkk = *(const float4*)(qkvw + 1024 + nb*16 + o*4);
      float4 wv = *(const float4*)(qkvw + 2048 + nb*16 + o*4);
      qs[s][lb*4+o]  = wq.x*xq[0]+wq.y*xq[1]+wq.z*xq[2]+wq.w*xq[3];
      ksm[s][lb*4+o] = wkk.x*xq[0]+wkk.y*xq[1]+wkk.z*xq[2]+wkk.w*xq[3];
      vsm[s][lb*4+o] = wv.x*xv[0]+wv.y*xv[1]+wv.z*xv[2]+wv.w*xv[3];
    }
  }
  __syncthreads();

  int i = t >> 2;
  int jq = t & 3;
  float mi = csum[i+1] + pmax[i];
  float rs = 0.f;
  for (int jj=0;jj<16;jj++){
    int j = jq*16 + jj;
    if (j <= i){
      const float4* qa = (const float4*)&qs[i][0];
      const float4* ka = (const float4*)&ksm[j][0];
      float dp = 0.f;
      #pragma unroll
      for (int kk=0;kk<16;kk++){
        float4 a = qa[kk], c = ka[kk];
        dp += a.x*c.x + a.y*c.y + a.z*c.z + a.w*c.w;
      }
      float val = dp * 0.125f * __expf(csum[i+1] - csum[j+1] + igl[j] - mi);
      cnm[i][j] = val;
      rs += val;
    }
  }
  rs += __shfl_xor(rs, 1, 4);
  rs += __shfl_xor(rs, 2, 4);
  if (jq == 0){
    float nm = fmaxf(fabsf(rs), __expf(-mi));
    nrec[i] = 1.f/(nm + 1e-6f);
  }
  __syncthreads();

  int d0 = jq*16;
  float acc[16];
  #pragma unroll
  for (int q=0;q<16;q++) acc[q]=0.f;
  float nr = nrec[i];
  for (int j=0;j<=i;j++){
    float cwv = cnm[i][j] * nr;
    const float4* va = (const float4*)&vsm[j][d0];
    #pragma unroll
    for (int q=0;q<4;q++){
      float4 v4 = va[q];
      acc[q*4+0] += cwv*v4.x; acc[q*4+1] += cwv*v4.y; acc[q*4+2] += cwv*v4.z; acc[q*4+3] += cwv*v4.w;
    }
  }
  float su=0.f, sq=0.f;
  #pragma unroll
  for (int q=0;q<16;q++){ su += acc[q]; sq += acc[q]*acc[q]; }
  su += __shfl_xor(su,1,4); su += __shfl_xor(su,2,4);
  sq += __shfl_xor(sq,1,4); sq += __shfl_xor(sq,2,4);
  float mu = su*(1.f/64.f);
  float var = sq*(1.f/64.f) - mu*mu;
  float ivr = rsqrtf(var + 1e-5f);
  const float* onw = onorm + hh*64 + d0;
  #pragma unroll
  for (int q=0;q<4;q++){
    float4 o4;
    o4.x = (acc[q*4+0]-mu)*ivr*onw[q*4+0];
    o4.y = (acc[q*4+1]-mu)*ivr*onw[q*4+1];
    o4.z = (acc[q*4+2]-mu)*ivr*onw[q*4+2];
    o4.w = (acc[q*4+3]-mu)*ivr*onw[q*4+3];
    *(float4*)(xmb + (size_t)i*256 + d0 + q*4) = o4;
  }
}

// ---------------- mLSTM combine + down-projection + residual ----------------
__global__ __launch_bounds__(256) void k_comb_down(
    float* __restrict__ h, const float* __restrict__ hln,
    const float* __restrict__ xc, const float* __restrict__ z,
    const float* __restrict__ skip, const float* __restrict__ down)
{
  __shared__ float comb[32][260];
  int t = threadIdx.x;
  size_t tok0 = (size_t)blockIdx.x*32;
  #pragma unroll
  for (int j=0;j<8;j++){
    int f4 = t + 256*j;
    int r = f4 >> 6, c4 = f4 & 63;
    size_t gi = (tok0 + r)*256 + c4*4;
    float4 a  = *(const float4*)(hln + gi);
    float4 xv = *(const float4*)(xc + gi);
    float4 zv = *(const float4*)(z + gi);
    float4 sk = *(const float4*)(skip + c4*4);
    float4 o;
    o.x = (a.x + sk.x*xv.x)*siluf(zv.x);
    o.y = (a.y + sk.y*xv.y)*siluf(zv.y);
    o.z = (a.z + sk.z*xv.z)*siluf(zv.z);
    o.w = (a.w + sk.w*xv.w)*siluf(zv.w);
    *(float4*)&comb[r][c4*4] = o;
  }
  __syncthreads();
  int tm = t>>4, om = t&15;
  int o0 = om*8, r0 = tm*2;
  float acc[2][8];
  #pragma unroll
  for (int j=0;j<8;j++){ acc[0][j]=0.f; acc[1][j]=0.f; }
  for (int k=0;k<256;k++){
    float x0 = comb[r0][k], x1 = comb[r0+1][k];
    const float4* w1 = (const float4*)(down + (size_t)k*128 + o0);
    float wv[8];
    *(float4*)&wv[0]=w1[0]; *(float4*)&wv[4]=w1[1];
    #pragma unroll
    for (int j=0;j<8;j++){ acc[0][j]+=x0*wv[j]; acc[1][j]+=x1*wv[j]; }
  }
  #pragma unroll
  for (int tt=0;tt<2;tt++){
    float* dst = h + (tok0 + r0 + tt)*128 + o0;
    float4 h0 = ((float4*)dst)[0], h1 = ((float4*)dst)[1];
    h0.x += acc[tt][0]; h0.y += acc[tt][1]; h0.z += acc[tt][2]; h0.w += acc[tt][3];
    h1.x += acc[tt][4]; h1.y += acc[tt][5]; h1.z += acc[tt][6]; h1.w += acc[tt][7];
    ((float4*)dst)[0]=h0; ((float4*)dst)[1]=h1;
  }
}

// ---------------- final LN + head ----------------
__global__ __launch_bounds__(256) void k_head(
    const float* __restrict__ h, const float* __restrict__ lnw,
    const float* __restrict__ w, const float* __restrict__ bias2,
    float* __restrict__ out)
{
  __shared__ float xln[32][132];
  __shared__ float red[32][8];
  __shared__ float red2[32][8];
  int t = threadIdx.x;
  size_t tok0 = (size_t)blockIdx.x * 32;

  ln_rows(h + tok0*128, lnw, &xln[0][0], 132, red, red2, t);
  __syncthreads();

  int tm = t>>4, om = t&15;
  int o0 = om*16, r0 = tm*2;
  float acc[2][16];
  #pragma unroll
  for (int j=0;j<16;j++){ acc[0][j]=0.f; acc[1][j]=0.f; }
  for (int k=0;k<128;k++){
    float x0 = xln[r0][k], x1 = xln[r0+1][k];
    const float4* wrow = (const float4*)(w + (size_t)k*256 + o0);
    #pragma unroll
    for (int q=0;q<4;q++){
      float4 wv = wrow[q];
      acc[0][q*4+0]+=x0*wv.x; acc[0][q*4+1]+=x0*wv.y; acc[0][q*4+2]+=x0*wv.z; acc[0][q*4+3]+=x0*wv.w;
      acc[1][q*4+0]+=x1*wv.x; acc[1][q*4+1]+=x1*wv.y; acc[1][q*4+2]+=x1*wv.z; acc[1][q*4+3]+=x1*wv.w;
    }
  }
  #pragma unroll
  for (int tt=0;tt<2;tt++){
    float* dst = out + (tok0 + r0 + tt)*256 + o0;
    #pragma unroll
    for (int q=0;q<4;q++){
      float4 bv = *(const float4*)(bias2 + o0 + q*4);
      float4 o4;
      o4.x = acc[tt][q*4+0] + bv.x;
      o4.y = acc[tt][q*4+1] + bv.y;
      o4.z = acc[tt][q*4+2] + bv.z;
      o4.w = acc[tt][q*4+3] + bv.w;
      ((float4*)dst)[q] = o4;
    }
  }
}

extern "C" void kernel_launch(void* const* d_in, const int* in_sizes, int n_in,
                              void* d_out, int out_size, void* d_ws, size_t ws_size,
                              hipStream_t stream)
{
  const int*   x      = (const int*)  d_in[0];
  const float* embed  = (const float*)d_in[1];
  const float* s_ln1  = (const float*)d_in[2];
  const float* s_gw   = (const float*)d_in[3];
  const float* s_rec  = (const float*)d_in[4];
  const float* s_bias = (const float*)d_in[5];
  const float* s_gn   = (const float*)d_in[6];
  const float* s_ln2  = (const float*)d_in[7];
  const float* s_ffu  = (const float*)d_in[8];
  const float* s_ffd  = (const float*)d_in[9];
  const float* m_ln1  = (const float*)d_in[10];
  const float* m_up   = (const float*)d_in[11];
  const float* m_cw   = (const float*)d_in[12];
  const float* m_cb   = (const float*)d_in[13];
  const float* m_qkv  = (const float*)d_in[14];
  const float* m_igw  = (const float*)d_in[15];
  const float* m_igb  = (const float*)d_in[16];
  const float* m_fgw  = (const float*)d_in[17];
  const float* m_fgb  = (const float*)d_in[18];
  const float* m_skip = (const float*)d_in[19];
  const float* m_onw  = (const float*)d_in[20];
  const float* m_down = (const float*)d_in[21];
  const float* m_ln2  = (const float*)d_in[22];
  const float* m_ffu  = (const float*)d_in[23];
  const float* m_ffd  = (const float*)d_in[24];
  const float* postln = (const float*)d_in[25];
  const float* headw  = (const float*)d_in[26];
  const float* headb  = (const float*)d_in[27];

  float* p = (float*)d_ws;
  float* hbuf = p; p += 4194304;                     // (B*S*D)
  size_t avail = ws_size / 4;
  const size_t need_full = 4194304ULL + 3ULL*8388608ULL + 2ULL*131072ULL;
  float* xmbuf;
  if (avail >= need_full){ xmbuf = p; p += 8388608; }
  else                   { xmbuf = (float*)d_out; }  // alias xm/h_ln into d_out if ws is small
  float* zbuf  = p; p += 8388608;
  float* xcbuf = p; p += 8388608;
  float* igbuf = p; p += 131072;
  float* fgbuf = p; p += 131072;

  k_embed<<<4096, 256, 0, stream>>>(x, embed, hbuf);

  for (int i=0;i<2;i++){
    k_slstm<<<512, 512, 0, stream>>>(hbuf, s_ln1+i*128, s_gw+i*16384, s_rec+i*16384,
                                     s_bias+i*512, s_gn+i*128);
    k_ffn<<<1024, 256, 0, stream>>>(hbuf, s_ln2+i*128, s_ffu+i*32768, s_ffd+i*16384);
    k_up<<<1024, 256, 0, stream>>>(hbuf, m_ln1+i*128, m_up+i*65536, xmbuf, zbuf);
    k_convgates<<<512, 256, 0, stream>>>(xmbuf, xcbuf, m_cw+i*1024, m_cb+i*256, m_qkv+i*3072,
                                         m_igw+i*3072, m_igb+i*4, m_fgw+i*3072, m_fgb+i*4,
                                         igbuf, fgbuf);
    k_attn<<<2048, 256, 0, stream>>>(xmbuf, xcbuf, m_qkv+i*3072, igbuf, fgbuf, m_onw+i*256);
    k_comb_down<<<1024, 256, 0, stream>>>(hbuf, xmbuf, xcbuf, zbuf, m_skip+i*256, m_down+i*32768);
    k_ffn<<<1024, 256, 0, stream>>>(hbuf, m_ln2+i*128, m_ffu+i*32768, m_ffd+i*16384);
  }

  k_head<<<1024, 256, 0, stream>>>(hbuf, postln, headw, headb, (float*)d_out);
}

// Round 3
// 2080.885 us; speedup vs baseline: 1.1848x; 1.1848x over previous
//
#include <hip/hip_runtime.h>
#include <math.h>

// B=512 S=64 D=128 V=256 NH=4 HD=32 INNER=256 NHM=4 DHM=64 BS=4 NB=64 K=4 FF=128

__device__ __forceinline__ float sigf(float x){ return 1.f/(1.f+__expf(-x)); }
__device__ __forceinline__ float siluf(float x){ return x/(1.f+__expf(-x)); }
__device__ __forceinline__ float logsigf(float x){ return fminf(x,0.f) - log1pf(__expf(-fabsf(x))); }
__device__ __forceinline__ float geluf(float x){
  return 0.5f*x*(1.f+tanhf(0.7978845608028654f*(x+0.044715f*x*x*x)));
}
__device__ __forceinline__ void sums4(float4 v, float& s, float& q){
  s += v.x+v.y+v.z+v.w;
  q += v.x*v.x+v.y*v.y+v.z*v.z+v.w*v.w;
}

// LayerNorm rows of 128; 8 threads per row; dst[r*dstride+c] = (x-mu)*rsqrt(var+eps)*w[c]
__device__ __forceinline__ void ln_rows(const float* __restrict__ src, const float* __restrict__ lnw,
                                        float* __restrict__ dst, int dstride,
                                        float (*red)[8], float (*red2)[8], int t)
{
  int r = t >> 3, l8 = t & 7;
  const float4* s4 = (const float4*)(src + (size_t)r*128 + l8*16);
  float4 v0=s4[0], v1=s4[1], v2=s4[2], v3=s4[3];
  float su=0.f, sq=0.f;
  sums4(v0,su,sq); sums4(v1,su,sq); sums4(v2,su,sq); sums4(v3,su,sq);
  red[r][l8]=su; red2[r][l8]=sq;
  __syncthreads();
  float ts=0.f, tq=0.f;
  #pragma unroll
  for (int k=0;k<8;k++){ ts+=red[r][k]; tq+=red2[r][k]; }
  float mu = ts*(1.f/128.f);
  float var = tq*(1.f/128.f) - mu*mu;
  float iv = rsqrtf(var+1e-5f);
  int c0 = l8*16;
  float vv[16];
  *(float4*)&vv[0]=v0; *(float4*)&vv[4]=v1; *(float4*)&vv[8]=v2; *(float4*)&vv[12]=v3;
  #pragma unroll
  for (int q2=0;q2<16;q2++) dst[r*dstride + c0 + q2] = (vv[q2]-mu)*iv*lnw[c0+q2];
}

// ---------------- embed ----------------
__global__ __launch_bounds__(256) void k_embed(const int* __restrict__ x, const float* __restrict__ embed,
                                               float* __restrict__ h)
{
  int idx4 = blockIdx.x*256 + threadIdx.x;      // over B*S*D/4 = 1048576 float4
  int tok = idx4 >> 5;
  int c4  = idx4 & 31;
  int id = x[tok];
  reinterpret_cast<float4*>(h)[idx4] = reinterpret_cast<const float4*>(embed)[id*32 + c4];
}

// ---------------- sLSTM (fused LN + scan + head-LN + residual) ----------------
__global__ __launch_bounds__(512) void k_slstm(
    float* __restrict__ h, const float* __restrict__ lnw,
    const float* __restrict__ gw, const float* __restrict__ rw,
    const float* __restrict__ bias, const float* __restrict__ gn)
{
  __shared__ float xh[64][128];     // LN-ed input, overwritten per-step with y
  __shared__ float hb[128];
  __shared__ float raw[512];
  __shared__ float red[64][8];
  __shared__ float red2[64][8];
  __shared__ float mu_s[64][4];
  __shared__ float iv_s[64][4];

  int t = threadIdx.x;
  int b = blockIdx.x;
  float* hrow = h + (size_t)b*8192;

  ln_rows(hrow, lnw, &xh[0][0], 128, red, red2, t);
  __syncthreads();

  int g  = t >> 7;
  int nh = (t >> 5) & 3;
  int e  = t & 31;
  float wg[32], wr[32];
  {
    const float4* g4 = (const float4*)(gw + (((g*4+nh)*32+e)*32));
    const float4* r4 = (const float4*)(rw + (((g*4+nh)*32+e)*32));
    #pragma unroll
    for (int q=0;q<8;q++){
      float4 a=g4[q]; wg[4*q]=a.x; wg[4*q+1]=a.y; wg[4*q+2]=a.z; wg[4*q+3]=a.w;
      float4 c=r4[q]; wr[4*q]=c.x; wr[4*q+1]=c.y; wr[4*q+2]=c.z; wr[4*q+3]=c.w;
    }
  }
  float bs = bias[(g*4+nh)*32+e];
  float c_s=0.f, n_s=0.f, m_s=0.f;
  if (t<128) hb[t]=0.f;
  __syncthreads();

  for (int s=0;s<64;s++){
    const float4* xr = (const float4*)&xh[s][nh*32];
    const float4* hr = (const float4*)&hb[nh*32];
    float acc = bs;
    #pragma unroll
    for (int q=0;q<8;q++){
      float4 xv = xr[q]; float4 hv = hr[q];
      acc += xv.x*wg[4*q+0] + xv.y*wg[4*q+1] + xv.z*wg[4*q+2] + xv.w*wg[4*q+3];
      acc += hv.x*wr[4*q+0] + hv.y*wr[4*q+1] + hv.z*wr[4*q+2] + hv.w*wr[4*q+3];
    }
    raw[t] = acc;
    __syncthreads();
    if (t < 128){
      float i_r = raw[t], f_r = raw[128+t], z_r = raw[256+t], o_r = raw[384+t];
      float lf = m_s + logsigf(f_r);
      float mn = fmaxf(i_r, lf);
      float iv = __expf(i_r-mn), fv = __expf(lf-mn);
      c_s = fv*c_s + iv*tanhf(z_r);
      n_s = fv*n_s + iv;
      m_s = mn;
      float hn = sigf(o_r)*c_s/n_s;
      hb[t] = hn;
      xh[s][t] = hn;
    }
    __syncthreads();
  }

  if (t < 256){
    int s = t>>2, n = t&3;
    const float4* yr = (const float4*)&xh[s][n*32];
    float su=0.f, sq=0.f;
    #pragma unroll
    for (int q=0;q<8;q++){ float4 v = yr[q]; sums4(v,su,sq); }
    float mu = su*(1.f/32.f);
    float var = sq*(1.f/32.f) - mu*mu;
    mu_s[s][n]=mu; iv_s[s][n]=rsqrtf(var+1e-5f);
  }
  __syncthreads();
  #pragma unroll
  for (int rr=0; rr<16; rr++){
    int idx = t + 512*rr;
    int s = idx>>7, c = idx&127;
    float y = (xh[s][c] - mu_s[s][c>>5]) * iv_s[s][c>>5] * gn[c];
    hrow[idx] += y;
  }
}

// ---------------- FFN (fused LN + up/gelu-gate + down + residual) ----------------
__global__ __launch_bounds__(256) void k_ffn(
    float* __restrict__ h, const float* __restrict__ lnw,
    const float* __restrict__ up, const float* __restrict__ down)
{
  __shared__ float xln[32][132];
  __shared__ float hid[32][132];
  __shared__ float red[32][8];
  __shared__ float red2[32][8];
  int t = threadIdx.x;
  size_t tok0 = (size_t)blockIdx.x * 32;

  ln_rows(h + tok0*128, lnw, &xln[0][0], 132, red, red2, t);
  __syncthreads();

  int tm = t>>4, om = t&15;
  int o0 = om*8, r0 = tm*2;
  float accg[2][8], accu[2][8];
  #pragma unroll
  for (int j=0;j<8;j++){ accg[0][j]=0.f; accg[1][j]=0.f; accu[0][j]=0.f; accu[1][j]=0.f; }
  for (int k=0;k<128;k++){
    float x0 = xln[r0][k], x1 = xln[r0+1][k];
    const float4* w1 = (const float4*)(up + (size_t)k*256 + o0);
    const float4* w2 = (const float4*)(up + (size_t)k*256 + 128 + o0);
    float wgv[8], wuv[8];
    *(float4*)&wgv[0]=w1[0]; *(float4*)&wgv[4]=w1[1];
    *(float4*)&wuv[0]=w2[0]; *(float4*)&wuv[4]=w2[1];
    #pragma unroll
    for (int j=0;j<8;j++){
      accg[0][j]+=x0*wgv[j]; accg[1][j]+=x1*wgv[j];
      accu[0][j]+=x0*wuv[j]; accu[1][j]+=x1*wuv[j];
    }
  }
  #pragma unroll
  for (int tt=0;tt<2;tt++)
    #pragma unroll
    for (int j=0;j<8;j++)
      hid[r0+tt][o0+j] = geluf(accg[tt][j]) * accu[tt][j];
  __syncthreads();

  float acc[2][8];
  #pragma unroll
  for (int j=0;j<8;j++){ acc[0][j]=0.f; acc[1][j]=0.f; }
  for (int k=0;k<128;k++){
    float x0 = hid[r0][k], x1 = hid[r0+1][k];
    const float4* w1 = (const float4*)(down + (size_t)k*128 + o0);
    float wv[8];
    *(float4*)&wv[0]=w1[0]; *(float4*)&wv[4]=w1[1];
    #pragma unroll
    for (int j=0;j<8;j++){ acc[0][j]+=x0*wv[j]; acc[1][j]+=x1*wv[j]; }
  }
  #pragma unroll
  for (int tt=0;tt<2;tt++){
    float* dst = h + (tok0 + r0 + tt)*128 + o0;
    float4 h0 = ((float4*)dst)[0], h1 = ((float4*)dst)[1];
    h0.x += acc[tt][0]; h0.y += acc[tt][1]; h0.z += acc[tt][2]; h0.w += acc[tt][3];
    h1.x += acc[tt][4]; h1.y += acc[tt][5]; h1.z += acc[tt][6]; h1.w += acc[tt][7];
    ((float4*)dst)[0]=h0; ((float4*)dst)[1]=h1;
  }
}

// ---------------- mLSTM up-projection (LN + 128->512, writes xm and z) ----------------
// 16 tokens/block, 256 threads: each thread 2 rows x 16 cols = 32 accumulators
__global__ __launch_bounds__(256) void k_up(
    const float* __restrict__ h, const float* __restrict__ lnw,
    const float* __restrict__ up, float* __restrict__ xm, float* __restrict__ z)
{
  __shared__ float xln[16][132];
  __shared__ float red[16][16];
  __shared__ float red2[16][16];
  int t = threadIdx.x;
  size_t tok0 = (size_t)blockIdx.x * 16;

  {
    int r = t >> 4, l = t & 15;
    const float4* s4 = (const float4*)(h + (tok0 + (size_t)r)*128 + l*8);
    float4 v0=s4[0], v1=s4[1];
    float su=0.f, sq=0.f; sums4(v0,su,sq); sums4(v1,su,sq);
    red[r][l]=su; red2[r][l]=sq;
    __syncthreads();
    float ts=0.f, tq=0.f;
    #pragma unroll
    for (int k2=0;k2<16;k2++){ ts+=red[r][k2]; tq+=red2[r][k2]; }
    float mu = ts*(1.f/128.f);
    float var = tq*(1.f/128.f) - mu*mu;
    float iv = rsqrtf(var+1e-5f);
    int c0 = l*8;
    float vv[8];
    *(float4*)&vv[0]=v0; *(float4*)&vv[4]=v1;
    #pragma unroll
    for (int q2=0;q2<8;q2++) xln[r][c0+q2] = (vv[q2]-mu)*iv*lnw[c0+q2];
  }
  __syncthreads();

  int tm = t >> 5;      // 0..7 -> row pair
  int om = t & 31;      // 0..31 -> 16-col group
  int r0 = tm*2, o0 = om*16;
  float acc0[16], acc1[16];
  #pragma unroll
  for (int j=0;j<16;j++){ acc0[j]=0.f; acc1[j]=0.f; }
  for (int k=0;k<128;k++){
    float x0 = xln[r0][k], x1 = xln[r0+1][k];
    const float4* wrow = (const float4*)(up + (size_t)k*512 + o0);
    float4 w0=wrow[0], w1=wrow[1], w2=wrow[2], w3=wrow[3];
    acc0[0] +=x0*w0.x; acc0[1] +=x0*w0.y; acc0[2] +=x0*w0.z; acc0[3] +=x0*w0.w;
    acc0[4] +=x0*w1.x; acc0[5] +=x0*w1.y; acc0[6] +=x0*w1.z; acc0[7] +=x0*w1.w;
    acc0[8] +=x0*w2.x; acc0[9] +=x0*w2.y; acc0[10]+=x0*w2.z; acc0[11]+=x0*w2.w;
    acc0[12]+=x0*w3.x; acc0[13]+=x0*w3.y; acc0[14]+=x0*w3.z; acc0[15]+=x0*w3.w;
    acc1[0] +=x1*w0.x; acc1[1] +=x1*w0.y; acc1[2] +=x1*w0.z; acc1[3] +=x1*w0.w;
    acc1[4] +=x1*w1.x; acc1[5] +=x1*w1.y; acc1[6] +=x1*w1.z; acc1[7] +=x1*w1.w;
    acc1[8] +=x1*w2.x; acc1[9] +=x1*w2.y; acc1[10]+=x1*w2.z; acc1[11]+=x1*w2.w;
    acc1[12]+=x1*w3.x; acc1[13]+=x1*w3.y; acc1[14]+=x1*w3.z; acc1[15]+=x1*w3.w;
  }
  #pragma unroll
  for (int tt=0;tt<2;tt++){
    const float* a = tt ? acc1 : acc0;
    float* dst = (o0 < 256) ? (xm + (tok0 + r0 + tt)*256 + o0)
                            : (z  + (tok0 + r0 + tt)*256 + (o0-256));
    #pragma unroll
    for (int q=0;q<4;q++){
      float4 w;
      w.x = a[q*4+0]; w.y = a[q*4+1]; w.z = a[q*4+2]; w.w = a[q*4+3];
      ((float4*)dst)[q] = w;
    }
  }
}

// ---------------- mLSTM conv + silu + gate projections ----------------
__global__ __launch_bounds__(256) void k_convgates(
    const float* __restrict__ xm, float* __restrict__ xc,
    const float* __restrict__ cw, const float* __restrict__ cb,
    const float* __restrict__ qkvw,
    const float* __restrict__ igw, const float* __restrict__ igb,
    const float* __restrict__ fgw, const float* __restrict__ fgb,
    float* __restrict__ ig, float* __restrict__ fg)
{
  __shared__ float xms[64][260];
  __shared__ float xcs[64][260];
  __shared__ float cwl[1024];
  __shared__ float cbl[256];
  int t = threadIdx.x;
  int b = blockIdx.x;
  const float* src = xm + (size_t)b*16384;

  #pragma unroll
  for (int j=0;j<16;j++){
    int f4 = t + 256*j;
    int r = f4 >> 6, c4 = f4 & 63;
    *(float4*)&xms[r][c4*4] = ((const float4*)src)[f4];
  }
  *(float4*)&cwl[t*4] = ((const float4*)cw)[t];       // 256 channels x 4 taps
  if (t < 64) *(float4*)&cbl[t*4] = ((const float4*)cb)[t];
  __syncthreads();

  int c4 = t & 63; int c0 = c4*4;
  int sr = t >> 6;
  float4 wk[4];
  #pragma unroll
  for (int k=0;k<4;k++)
    wk[k] = make_float4(cwl[(c0+0)*4+k], cwl[(c0+1)*4+k], cwl[(c0+2)*4+k], cwl[(c0+3)*4+k]);
  float4 bias4 = *(float4*)&cbl[c0];
  for (int j=0;j<16;j++){
    int s = sr*16 + j;
    float4 a = bias4;
    #pragma unroll
    for (int k=0;k<4;k++){
      int sp = s - 3 + k;
      if (sp >= 0){
        float4 xv = *(const float4*)&xms[sp][c0];
        a.x += xv.x*wk[k].x; a.y += xv.y*wk[k].y; a.z += xv.z*wk[k].z; a.w += xv.w*wk[k].w;
      }
    }
    a.x = siluf(a.x); a.y = siluf(a.y); a.z = siluf(a.z); a.w = siluf(a.w);
    *(float4*)&xcs[s][c0] = a;
    *(float4*)(xc + (size_t)b*16384 + (size_t)s*256 + c0) = a;
  }
  __syncthreads();

  int s = t >> 2, p = t & 3;
  float gig[4] = {0.f,0.f,0.f,0.f}, gfg[4] = {0.f,0.f,0.f,0.f};
  for (int gi = p*192; gi < p*192+192; gi++){
    int which = gi >> 8;
    int idx = gi & 255;
    int nb = idx >> 2, o = idx & 3;
    float4 w = *(const float4*)(qkvw + which*1024 + nb*16 + o*4);
    const float* s2 = (which==2) ? &xms[s][nb*4] : &xcs[s][nb*4];
    float val = w.x*s2[0] + w.y*s2[1] + w.z*s2[2] + w.w*s2[3];
    float4 gw4 = *(const float4*)(igw + (size_t)gi*4);
    float4 fw4 = *(const float4*)(fgw + (size_t)gi*4);
    gig[0]+=val*gw4.x; gig[1]+=val*gw4.y; gig[2]+=val*gw4.z; gig[3]+=val*gw4.w;
    gfg[0]+=val*fw4.x; gfg[1]+=val*fw4.y; gfg[2]+=val*fw4.z; gfg[3]+=val*fw4.w;
  }
  #pragma unroll
  for (int m=0;m<4;m++){
    gig[m] += __shfl_xor(gig[m],1,4); gig[m] += __shfl_xor(gig[m],2,4);
    gfg[m] += __shfl_xor(gfg[m],1,4); gfg[m] += __shfl_xor(gfg[m],2,4);
  }
  if (p == 0){
    #pragma unroll
    for (int m=0;m<4;m++){
      ig[(size_t)b*256 + m*64 + s] = gig[m] + igb[m];
      fg[(size_t)b*256 + m*64 + s] = gfg[m] + fgb[m];
    }
  }
}

// ---------------- mLSTM attention per (b, head); writes head-LN'ed h into xm buffer ----------------
__global__ __launch_bounds__(256) void k_attn(
    float* __restrict__ xm, const float* __restrict__ xc,
    const float* __restrict__ qkvw,
    const float* __restrict__ igp, const float* __restrict__ fgp,
    const float* __restrict__ onorm)
{
  __shared__ float qs[64][68];
  __shared__ float ksm[64][68];
  __shared__ float vsm[64][68];
  __shared__ float xcl[64][68];
  __shared__ float xml[64][68];
  __shared__ float cnm[64][65];
  __shared__ float csum[65];
  __shared__ float pmax[64];
  __shared__ float igl[64];
  __shared__ float lfs[64];
  __shared__ float nrec[64];

  int t = threadIdx.x;
  int b = blockIdx.x >> 2, hh = blockIdx.x & 3;
  const float* xcb = xc + (size_t)b*16384 + hh*64;
  float* xmb = xm + (size_t)b*16384 + hh*64;

  #pragma unroll
  for (int j=0;j<4;j++){
    int u = t + 256*j;
    int r = u >> 4, q4 = u & 15;
    *(float4*)&xcl[r][q4*4] = *(const float4*)(xcb + (size_t)r*256 + q4*4);
    *(float4*)&xml[r][q4*4] = *(const float4*)(xmb + (size_t)r*256 + q4*4);
  }
  if (t < 64){
    lfs[t] = logsigf(fgp[(size_t)b*256 + hh*64 + t]);
    igl[t] = igp[(size_t)b*256 + hh*64 + t];
  }
  __syncthreads();
  if (t == 0){
    float cacc = 0.f, pm = -1e30f;
    csum[0] = 0.f;
    for (int s=0;s<64;s++){
      cacc += lfs[s];
      csum[s+1] = cacc;
      pm = fmaxf(pm, igl[s] - cacc);
      pmax[s] = pm;
    }
  }
  #pragma unroll
  for (int j=0;j<4;j++){
    int u = t + 256*j;
    int s = u >> 4, lb = u & 15;
    int nb = hh*16 + lb;
    const float* xq = &xcl[s][lb*4];
    const float* xv = &xml[s][lb*4];
    #pragma unroll
    for (int o=0;o<4;o++){
      float4 wq = *(const float4*)(qkvw + nb*16 + o*4);
      float4 wkk = *(const float4*)(qkvw + 1024 + nb*16 + o*4);
      float4 wv = *(const float4*)(qkvw + 2048 + nb*16 + o*4);
      qs[s][lb*4+o]  = wq.x*xq[0]+wq.y*xq[1]+wq.z*xq[2]+wq.w*xq[3];
      ksm[s][lb*4+o] = wkk.x*xq[0]+wkk.y*xq[1]+wkk.z*xq[2]+wkk.w*xq[3];
      vsm[s][lb*4+o] = wv.x*xv[0]+wv.y*xv[1]+wv.z*xv[2]+wv.w*xv[3];
    }
  }
  __syncthreads();

  int i = t >> 2;
  int jq = t & 3;
  float mi = csum[i+1] + pmax[i];
  float rs = 0.f;
  for (int jj=0;jj<16;jj++){
    int j = jq*16 + jj;
    if (j <= i){
      const float4* qa = (const float4*)&qs[i][0];
      const float4* ka = (const float4*)&ksm[j][0];
      float dp = 0.f;
      #pragma unroll
      for (int kk=0;kk<16;kk++){
        float4 a = qa[kk], c = ka[kk];
        dp += a.x*c.x + a.y*c.y + a.z*c.z + a.w*c.w;
      }
      float val = dp * 0.125f * __expf(csum[i+1] - csum[j+1] + igl[j] - mi);
      cnm[i][j] = val;
      rs += val;
    }
  }
  rs += __shfl_xor(rs, 1, 4);
  rs += __shfl_xor(rs, 2, 4);
  if (jq == 0){
    float nm = fmaxf(fabsf(rs), __expf(-mi));
    nrec[i] = 1.f/(nm + 1e-6f);
  }
  __syncthreads();

  int d0 = jq*16;
  float acc[16];
  #pragma unroll
  for (int q=0;q<16;q++) acc[q]=0.f;
  float nr = nrec[i];
  for (int j=0;j<=i;j++){
    float cwv = cnm[i][j] * nr;
    const float4* va = (const float4*)&vsm[j][d0];
    #pragma unroll
    for (int q=0;q<4;q++){
      float4 v4 = va[q];
      acc[q*4+0] += cwv*v4.x; acc[q*4+1] += cwv*v4.y; acc[q*4+2] += cwv*v4.z; acc[q*4+3] += cwv*v4.w;
    }
  }
  float su=0.f, sq=0.f;
  #pragma unroll
  for (int q=0;q<16;q++){ su += acc[q]; sq += acc[q]*acc[q]; }
  su += __shfl_xor(su,1,4); su += __shfl_xor(su,2,4);
  sq += __shfl_xor(sq,1,4); sq += __shfl_xor(sq,2,4);
  float mu = su*(1.f/64.f);
  float var = sq*(1.f/64.f) - mu*mu;
  float ivr = rsqrtf(var + 1e-5f);
  const float* onw = onorm + hh*64 + d0;
  #pragma unroll
  for (int q=0;q<4;q++){
    float4 o4;
    o4.x = (acc[q*4+0]-mu)*ivr*onw[q*4+0];
    o4.y = (acc[q*4+1]-mu)*ivr*onw[q*4+1];
    o4.z = (acc[q*4+2]-mu)*ivr*onw[q*4+2];
    o4.w = (acc[q*4+3]-mu)*ivr*onw[q*4+3];
    *(float4*)(xmb + (size_t)i*256 + d0 + q*4) = o4;
  }
}

// ---------------- mLSTM combine + down-projection + residual ----------------
__global__ __launch_bounds__(256) void k_comb_down(
    float* __restrict__ h, const float* __restrict__ hln,
    const float* __restrict__ xc, const float* __restrict__ z,
    const float* __restrict__ skip, const float* __restrict__ down)
{
  __shared__ float comb[32][260];
  int t = threadIdx.x;
  size_t tok0 = (size_t)blockIdx.x*32;
  #pragma unroll
  for (int j=0;j<8;j++){
    int f4 = t + 256*j;
    int r = f4 >> 6, c4 = f4 & 63;
    size_t gi = (tok0 + r)*256 + c4*4;
    float4 a  = *(const float4*)(hln + gi);
    float4 xv = *(const float4*)(xc + gi);
    float4 zv = *(const float4*)(z + gi);
    float4 sk = *(const float4*)(skip + c4*4);
    float4 o;
    o.x = (a.x + sk.x*xv.x)*siluf(zv.x);
    o.y = (a.y + sk.y*xv.y)*siluf(zv.y);
    o.z = (a.z + sk.z*xv.z)*siluf(zv.z);
    o.w = (a.w + sk.w*xv.w)*siluf(zv.w);
    *(float4*)&comb[r][c4*4] = o;
  }
  __syncthreads();
  int tm = t>>4, om = t&15;
  int o0 = om*8, r0 = tm*2;
  float acc[2][8];
  #pragma unroll
  for (int j=0;j<8;j++){ acc[0][j]=0.f; acc[1][j]=0.f; }
  for (int k=0;k<256;k++){
    float x0 = comb[r0][k], x1 = comb[r0+1][k];
    const float4* w1 = (const float4*)(down + (size_t)k*128 + o0);
    float wv[8];
    *(float4*)&wv[0]=w1[0]; *(float4*)&wv[4]=w1[1];
    #pragma unroll
    for (int j=0;j<8;j++){ acc[0][j]+=x0*wv[j]; acc[1][j]+=x1*wv[j]; }
  }
  #pragma unroll
  for (int tt=0;tt<2;tt++){
    float* dst = h + (tok0 + r0 + tt)*128 + o0;
    float4 h0 = ((float4*)dst)[0], h1 = ((float4*)dst)[1];
    h0.x += acc[tt][0]; h0.y += acc[tt][1]; h0.z += acc[tt][2]; h0.w += acc[tt][3];
    h1.x += acc[tt][4]; h1.y += acc[tt][5]; h1.z += acc[tt][6]; h1.w += acc[tt][7];
    ((float4*)dst)[0]=h0; ((float4*)dst)[1]=h1;
  }
}

// ---------------- final LN + head ----------------
__global__ __launch_bounds__(256) void k_head(
    const float* __restrict__ h, const float* __restrict__ lnw,
    const float* __restrict__ w, const float* __restrict__ bias2,
    float* __restrict__ out)
{
  __shared__ float xln[32][132];
  __shared__ float red[32][8];
  __shared__ float red2[32][8];
  int t = threadIdx.x;
  size_t tok0 = (size_t)blockIdx.x * 32;

  ln_rows(h + tok0*128, lnw, &xln[0][0], 132, red, red2, t);
  __syncthreads();

  int tm = t>>4, om = t&15;
  int o0 = om*16, r0 = tm*2;
  float acc[2][16];
  #pragma unroll
  for (int j=0;j<16;j++){ acc[0][j]=0.f; acc[1][j]=0.f; }
  for (int k=0;k<128;k++){
    float x0 = xln[r0][k], x1 = xln[r0+1][k];
    const float4* wrow = (const float4*)(w + (size_t)k*256 + o0);
    #pragma unroll
    for (int q=0;q<4;q++){
      float4 wv = wrow[q];
      acc[0][q*4+0]+=x0*wv.x; acc[0][q*4+1]+=x0*wv.y; acc[0][q*4+2]+=x0*wv.z; acc[0][q*4+3]+=x0*wv.w;
      acc[1][q*4+0]+=x1*wv.x; acc[1][q*4+1]+=x1*wv.y; acc[1][q*4+2]+=x1*wv.z; acc[1][q*4+3]+=x1*wv.w;
    }
  }
  #pragma unroll
  for (int tt=0;tt<2;tt++){
    float* dst = out + (tok0 + r0 + tt)*256 + o0;
    #pragma unroll
    for (int q=0;q<4;q++){
      float4 bv = *(const float4*)(bias2 + o0 + q*4);
      float4 o4;
      o4.x = acc[tt][q*4+0] + bv.x;
      o4.y = acc[tt][q*4+1] + bv.y;
      o4.z = acc[tt][q*4+2] + bv.z;
      o4.w = acc[tt][q*4+3] + bv.w;
      ((float4*)dst)[q] = o4;
    }
  }
}

extern "C" void kernel_launch(void* const* d_in, const int* in_sizes, int n_in,
                              void* d_out, int out_size, void* d_ws, size_t ws_size,
                              hipStream_t stream)
{
  const int*   x      = (const int*)  d_in[0];
  const float* embed  = (const float*)d_in[1];
  const float* s_ln1  = (const float*)d_in[2];
  const float* s_gw   = (const float*)d_in[3];
  const float* s_rec  = (const float*)d_in[4];
  const float* s_bias = (const float*)d_in[5];
  const float* s_gn   = (const float*)d_in[6];
  const float* s_ln2  = (const float*)d_in[7];
  const float* s_ffu  = (const float*)d_in[8];
  const float* s_ffd  = (const float*)d_in[9];
  const float* m_ln1  = (const float*)d_in[10];
  const float* m_up   = (const float*)d_in[11];
  const float* m_cw   = (const float*)d_in[12];
  const float* m_cb   = (const float*)d_in[13];
  const float* m_qkv  = (const float*)d_in[14];
  const float* m_igw  = (const float*)d_in[15];
  const float* m_igb  = (const float*)d_in[16];
  const float* m_fgw  = (const float*)d_in[17];
  const float* m_fgb  = (const float*)d_in[18];
  const float* m_skip = (const float*)d_in[19];
  const float* m_onw  = (const float*)d_in[20];
  const float* m_down = (const float*)d_in[21];
  const float* m_ln2  = (const float*)d_in[22];
  const float* m_ffu  = (const float*)d_in[23];
  const float* m_ffd  = (const float*)d_in[24];
  const float* postln = (const float*)d_in[25];
  const float* headw  = (const float*)d_in[26];
  const float* headb  = (const float*)d_in[27];

  float* p = (float*)d_ws;
  float* hbuf = p; p += 4194304;                     // (B*S*D)
  size_t avail = ws_size / 4;
  const size_t need_full = 4194304ULL + 3ULL*8388608ULL + 2ULL*131072ULL;
  float* xmbuf;
  if (avail >= need_full){ xmbuf = p; p += 8388608; }
  else                   { xmbuf = (float*)d_out; }  // alias xm/h_ln into d_out if ws is small
  float* zbuf  = p; p += 8388608;
  float* xcbuf = p; p += 8388608;
  float* igbuf = p; p += 131072;
  float* fgbuf = p; p += 131072;

  k_embed<<<4096, 256, 0, stream>>>(x, embed, hbuf);

  for (int i=0;i<2;i++){
    k_slstm<<<512, 512, 0, stream>>>(hbuf, s_ln1+i*128, s_gw+i*16384, s_rec+i*16384,
                                     s_bias+i*512, s_gn+i*128);
    k_ffn<<<1024, 256, 0, stream>>>(hbuf, s_ln2+i*128, s_ffu+i*32768, s_ffd+i*16384);
    k_up<<<2048, 256, 0, stream>>>(hbuf, m_ln1+i*128, m_up+i*65536, xmbuf, zbuf);
    k_convgates<<<512, 256, 0, stream>>>(xmbuf, xcbuf, m_cw+i*1024, m_cb+i*256, m_qkv+i*3072,
                                         m_igw+i*3072, m_igb+i*4, m_fgw+i*3072, m_fgb+i*4,
                                         igbuf, fgbuf);
    k_attn<<<2048, 256, 0, stream>>>(xmbuf, xcbuf, m_qkv+i*3072, igbuf, fgbuf, m_onw+i*256);
    k_comb_down<<<1024, 256, 0, stream>>>(hbuf, xmbuf, xcbuf, zbuf, m_skip+i*256, m_down+i*32768);
    k_ffn<<<1024, 256, 0, stream>>>(hbuf, m_ln2+i*128, m_ffu+i*32768, m_ffd+i*16384);
  }

  k_head<<<1024, 256, 0, stream>>>(hbuf, postln, headw, headb, (float*)d_out);
}

// Round 5
// 1520.249 us; speedup vs baseline: 1.6217x; 1.3688x over previous
//
#include <hip/hip_runtime.h>
#include <math.h>

// B=512 S=64 D=128 V=256 NH=4 HD=32 INNER=256 NHM=4 DHM=64 BS=4 NB=64 K=4 FF=128

__device__ __forceinline__ float sigf(float x){ return 1.f/(1.f+__expf(-x)); }
__device__ __forceinline__ float siluf(float x){ return x/(1.f+__expf(-x)); }
__device__ __forceinline__ float logsigf(float x){ return fminf(x,0.f) - log1pf(__expf(-fabsf(x))); }
__device__ __forceinline__ float geluf(float x){
  return 0.5f*x*(1.f+tanhf(0.7978845608028654f*(x+0.044715f*x*x*x)));
}
__device__ __forceinline__ void sums4(float4 v, float& s, float& q){
  s += v.x+v.y+v.z+v.w;
  q += v.x*v.x+v.y*v.y+v.z*v.z+v.w*v.w;
}

// LayerNorm rows of 128; 8 threads per row; dst[r*dstride+c] = (x-mu)*rsqrt(var+eps)*w[c]
__device__ __forceinline__ void ln_rows(const float* __restrict__ src, const float* __restrict__ lnw,
                                        float* __restrict__ dst, int dstride,
                                        float (*red)[8], float (*red2)[8], int t)
{
  int r = t >> 3, l8 = t & 7;
  const float4* s4 = (const float4*)(src + (size_t)r*128 + l8*16);
  float4 v0=s4[0], v1=s4[1], v2=s4[2], v3=s4[3];
  float su=0.f, sq=0.f;
  sums4(v0,su,sq); sums4(v1,su,sq); sums4(v2,su,sq); sums4(v3,su,sq);
  red[r][l8]=su; red2[r][l8]=sq;
  __syncthreads();
  float ts=0.f, tq=0.f;
  #pragma unroll
  for (int k=0;k<8;k++){ ts+=red[r][k]; tq+=red2[r][k]; }
  float mu = ts*(1.f/128.f);
  float var = tq*(1.f/128.f) - mu*mu;
  float iv = rsqrtf(var+1e-5f);
  int c0 = l8*16;
  float vv[16];
  *(float4*)&vv[0]=v0; *(float4*)&vv[4]=v1; *(float4*)&vv[8]=v2; *(float4*)&vv[12]=v3;
  #pragma unroll
  for (int q2=0;q2<16;q2++) dst[r*dstride + c0 + q2] = (vv[q2]-mu)*iv*lnw[c0+q2];
}

// ---------------- embed ----------------
__global__ __launch_bounds__(256) void k_embed(const int* __restrict__ x, const float* __restrict__ embed,
                                               float* __restrict__ h)
{
  int idx4 = blockIdx.x*256 + threadIdx.x;      // over B*S*D/4 = 1048576 float4
  int tok = idx4 >> 5;
  int c4  = idx4 & 31;
  int id = x[tok];
  reinterpret_cast<float4*>(h)[idx4] = reinterpret_cast<const float4*>(embed)[id*32 + c4];
}

// ---------------- sLSTM (fused LN + scan + head-LN + residual) ----------------
__global__ __launch_bounds__(512) void k_slstm(
    float* __restrict__ h, const float* __restrict__ lnw,
    const float* __restrict__ gw, const float* __restrict__ rw,
    const float* __restrict__ bias, const float* __restrict__ gn)
{
  __shared__ float xh[64][128];     // LN-ed input, overwritten per-step with y
  __shared__ float hb[128];
  __shared__ float raw[512];
  __shared__ float red[64][8];
  __shared__ float red2[64][8];
  __shared__ float mu_s[64][4];
  __shared__ float iv_s[64][4];

  int t = threadIdx.x;
  int b = blockIdx.x;
  float* hrow = h + (size_t)b*8192;

  ln_rows(hrow, lnw, &xh[0][0], 128, red, red2, t);
  __syncthreads();

  int g  = t >> 7;
  int nh = (t >> 5) & 3;
  int e  = t & 31;
  float wg[32], wr[32];
  {
    const float4* g4 = (const float4*)(gw + (((g*4+nh)*32+e)*32));
    const float4* r4 = (const float4*)(rw + (((g*4+nh)*32+e)*32));
    #pragma unroll
    for (int q=0;q<8;q++){
      float4 a=g4[q]; wg[4*q]=a.x; wg[4*q+1]=a.y; wg[4*q+2]=a.z; wg[4*q+3]=a.w;
      float4 c=r4[q]; wr[4*q]=c.x; wr[4*q+1]=c.y; wr[4*q+2]=c.z; wr[4*q+3]=c.w;
    }
  }
  float bs = bias[(g*4+nh)*32+e];
  float c_s=0.f, n_s=0.f, m_s=0.f;
  if (t<128) hb[t]=0.f;
  __syncthreads();

  for (int s=0;s<64;s++){
    const float4* xr = (const float4*)&xh[s][nh*32];
    const float4* hr = (const float4*)&hb[nh*32];
    float acc = bs;
    #pragma unroll
    for (int q=0;q<8;q++){
      float4 xv = xr[q]; float4 hv = hr[q];
      acc += xv.x*wg[4*q+0] + xv.y*wg[4*q+1] + xv.z*wg[4*q+2] + xv.w*wg[4*q+3];
      acc += hv.x*wr[4*q+0] + hv.y*wr[4*q+1] + hv.z*wr[4*q+2] + hv.w*wr[4*q+3];
    }
    raw[t] = acc;
    __syncthreads();
    if (t < 128){
      float i_r = raw[t], f_r = raw[128+t], z_r = raw[256+t], o_r = raw[384+t];
      float lf = m_s + logsigf(f_r);
      float mn = fmaxf(i_r, lf);
      float iv = __expf(i_r-mn), fv = __expf(lf-mn);
      c_s = fv*c_s + iv*tanhf(z_r);
      n_s = fv*n_s + iv;
      m_s = mn;
      float hn = sigf(o_r)*c_s/n_s;
      hb[t] = hn;
      xh[s][t] = hn;
    }
    __syncthreads();
  }

  if (t < 256){
    int s = t>>2, n = t&3;
    const float4* yr = (const float4*)&xh[s][n*32];
    float su=0.f, sq=0.f;
    #pragma unroll
    for (int q=0;q<8;q++){ float4 v = yr[q]; sums4(v,su,sq); }
    float mu = su*(1.f/32.f);
    float var = sq*(1.f/32.f) - mu*mu;
    mu_s[s][n]=mu; iv_s[s][n]=rsqrtf(var+1e-5f);
  }
  __syncthreads();
  #pragma unroll
  for (int rr=0; rr<16; rr++){
    int idx = t + 512*rr;
    int s = idx>>7, c = idx&127;
    float y = (xh[s][c] - mu_s[s][c>>5]) * iv_s[s][c>>5] * gn[c];
    hrow[idx] += y;
  }
}

// ---------------- FFN (fused LN + up/gelu-gate + down + residual), LDS-staged weights ----------------
// 32 tokens/block, grid = 1024
__global__ __launch_bounds__(256) void k_ffn(
    float* __restrict__ h, const float* __restrict__ lnw,
    const float* __restrict__ up, const float* __restrict__ down)
{
  __shared__ float xln[32][132];
  __shared__ float hid[32][132];
  __shared__ float bws[2][16][256];
  __shared__ float red[32][8];
  __shared__ float red2[32][8];
  int t = threadIdx.x;
  size_t tok0 = (size_t)blockIdx.x * 32;

  ln_rows(h + tok0*128, lnw, &xln[0][0], 132, red, red2, t);
  __syncthreads();

  int r0 = (t >> 5) * 4;      // 4 rows
  int c0 = (t & 31) * 4;      // 4 cols (of 128)

  // ---- GEMM1: xln(32x128) @ up(128x256) -> gelu(g)*u -> hid(32x128)
  {
    float4 regs[4];
    auto stage = [&](int kc){
      #pragma unroll
      for (int j=0;j<4;j++){
        int idx = t + 256*j;
        int row = idx >> 6, c4 = idx & 63;
        regs[j] = *(const float4*)(up + (size_t)(kc*16+row)*256 + c4*4);
      }
    };
    auto wrt = [&](int buf){
      #pragma unroll
      for (int j=0;j<4;j++){
        int idx = t + 256*j;
        int row = idx >> 6, c4 = idx & 63;
        *(float4*)&bws[buf][row][c4*4] = regs[j];
      }
    };
    stage(0); wrt(0);
    __syncthreads();
    float4 ag[4], au[4];
    #pragma unroll
    for (int i=0;i<4;i++){ ag[i]=make_float4(0,0,0,0); au[i]=make_float4(0,0,0,0); }
    for (int kc=0;kc<8;kc++){
      if (kc<7) stage(kc+1);
      int buf = kc & 1;
      #pragma unroll
      for (int k=0;k<16;k++){
        float4 wg = *(float4*)&bws[buf][k][c0];
        float4 wu = *(float4*)&bws[buf][k][c0+128];
        int kk = kc*16 + k;
        #pragma unroll
        for (int i=0;i<4;i++){
          float xv = xln[r0+i][kk];
          ag[i].x+=xv*wg.x; ag[i].y+=xv*wg.y; ag[i].z+=xv*wg.z; ag[i].w+=xv*wg.w;
          au[i].x+=xv*wu.x; au[i].y+=xv*wu.y; au[i].z+=xv*wu.z; au[i].w+=xv*wu.w;
        }
      }
      if (kc<7) wrt(buf^1);
      __syncthreads();
    }
    #pragma unroll
    for (int i=0;i<4;i++){
      hid[r0+i][c0+0] = geluf(ag[i].x)*au[i].x;
      hid[r0+i][c0+1] = geluf(ag[i].y)*au[i].y;
      hid[r0+i][c0+2] = geluf(ag[i].z)*au[i].z;
      hid[r0+i][c0+3] = geluf(ag[i].w)*au[i].w;
    }
  }
  __syncthreads();

  // ---- GEMM2: hid(32x128) @ down(128x128) -> += h
  {
    float (*bw2)[16][128] = (float (*)[16][128])bws;
    float4 regs[2];
    auto stage = [&](int kc){
      #pragma unroll
      for (int j=0;j<2;j++){
        int idx = t + 256*j;
        int row = idx >> 5, c4 = idx & 31;
        regs[j] = *(const float4*)(down + (size_t)(kc*16+row)*128 + c4*4);
      }
    };
    auto wrt = [&](int buf){
      #pragma unroll
      for (int j=0;j<2;j++){
        int idx = t + 256*j;
        int row = idx >> 5, c4 = idx & 31;
        *(float4*)&bw2[buf][row][c4*4] = regs[j];
      }
    };
    stage(0); wrt(0);
    __syncthreads();
    float4 a2[4];
    #pragma unroll
    for (int i=0;i<4;i++) a2[i]=make_float4(0,0,0,0);
    for (int kc=0;kc<8;kc++){
      if (kc<7) stage(kc+1);
      int buf = kc & 1;
      #pragma unroll
      for (int k=0;k<16;k++){
        float4 wv = *(float4*)&bw2[buf][k][c0];
        int kk = kc*16 + k;
        #pragma unroll
        for (int i=0;i<4;i++){
          float xv = hid[r0+i][kk];
          a2[i].x+=xv*wv.x; a2[i].y+=xv*wv.y; a2[i].z+=xv*wv.z; a2[i].w+=xv*wv.w;
        }
      }
      if (kc<7) wrt(buf^1);
      __syncthreads();
    }
    #pragma unroll
    for (int i=0;i<4;i++){
      float* dstp = h + (tok0 + r0 + i)*128 + c0;
      float4 hv = *(float4*)dstp;
      hv.x += a2[i].x; hv.y += a2[i].y; hv.z += a2[i].z; hv.w += a2[i].w;
      *(float4*)dstp = hv;
    }
  }
}

// ---------------- mLSTM up-projection (LN + 128->512), LDS-staged weights ----------------
// 64 tokens x 128 cols per block; grid = 512*4
__global__ __launch_bounds__(256) void k_up(
    const float* __restrict__ h, const float* __restrict__ lnw,
    const float* __restrict__ up, float* __restrict__ xm, float* __restrict__ z)
{
  __shared__ float xln[64][132];
  __shared__ float bw[2][32][128];
  __shared__ float red[64][4];
  __shared__ float red2[64][4];
  int t = threadIdx.x;
  int mt = blockIdx.x >> 2, nt = blockIdx.x & 3;
  size_t tok0 = (size_t)mt * 64;
  int n0 = nt * 128;

  // LN: 64 rows, 4 threads/row (32 cols each)
  {
    int r = t >> 2, l = t & 3;
    const float4* s4 = (const float4*)(h + (tok0 + (size_t)r)*128 + l*32);
    float4 v[8];
    float su=0.f, sq=0.f;
    #pragma unroll
    for (int q=0;q<8;q++){ v[q]=s4[q]; sums4(v[q],su,sq); }
    red[r][l]=su; red2[r][l]=sq;
    __syncthreads();
    float ts=red[r][0]+red[r][1]+red[r][2]+red[r][3];
    float tq=red2[r][0]+red2[r][1]+red2[r][2]+red2[r][3];
    float mu=ts*(1.f/128.f);
    float var=tq*(1.f/128.f)-mu*mu;
    float iv=rsqrtf(var+1e-5f);
    int cb=l*32;
    #pragma unroll
    for (int q=0;q<8;q++){
      xln[r][cb+q*4+0]=(v[q].x-mu)*iv*lnw[cb+q*4+0];
      xln[r][cb+q*4+1]=(v[q].y-mu)*iv*lnw[cb+q*4+1];
      xln[r][cb+q*4+2]=(v[q].z-mu)*iv*lnw[cb+q*4+2];
      xln[r][cb+q*4+3]=(v[q].w-mu)*iv*lnw[cb+q*4+3];
    }
  }

  float4 regs[4];
  auto stage = [&](int kc){
    #pragma unroll
    for (int j=0;j<4;j++){
      int idx = t + 256*j;
      int row = idx >> 5, c4 = idx & 31;
      regs[j] = *(const float4*)(up + (size_t)(kc*32+row)*512 + n0 + c4*4);
    }
  };
  auto wrt = [&](int buf){
    #pragma unroll
    for (int j=0;j<4;j++){
      int idx = t + 256*j;
      int row = idx >> 5, c4 = idx & 31;
      *(float4*)&bw[buf][row][c4*4] = regs[j];
    }
  };
  stage(0); wrt(0);
  __syncthreads();

  int r0 = (t >> 5) * 8;      // 8 rows
  int c0 = (t & 31) * 4;      // 4 cols (of 128)
  float4 acc4[8];
  #pragma unroll
  for (int i=0;i<8;i++) acc4[i]=make_float4(0,0,0,0);

  for (int kc=0;kc<4;kc++){
    if (kc<3) stage(kc+1);
    int buf = kc & 1;
    #pragma unroll 8
    for (int k=0;k<32;k++){
      float4 wv = *(float4*)&bw[buf][k][c0];
      int kk = kc*32 + k;
      #pragma unroll
      for (int i=0;i<8;i++){
        float xv = xln[r0+i][kk];
        acc4[i].x += xv*wv.x; acc4[i].y += xv*wv.y; acc4[i].z += xv*wv.z; acc4[i].w += xv*wv.w;
      }
    }
    if (kc<3) wrt(buf^1);
    __syncthreads();
  }

  float* dst; int cbase;
  if (n0 < 256){ dst = xm; cbase = n0 + c0; }
  else         { dst = z;  cbase = n0 - 256 + c0; }
  #pragma unroll
  for (int i=0;i<8;i++)
    *(float4*)(dst + (tok0 + r0 + i)*256 + cbase) = acc4[i];
}

// ---------------- mLSTM conv + silu + gate projections ----------------
__global__ __launch_bounds__(256) void k_convgates(
    const float* __restrict__ xm, float* __restrict__ xc,
    const float* __restrict__ cw, const float* __restrict__ cb,
    const float* __restrict__ qkvw,
    const float* __restrict__ igw, const float* __restrict__ igb,
    const float* __restrict__ fgw, const float* __restrict__ fgb,
    float* __restrict__ ig, float* __restrict__ fg)
{
  __shared__ float xms[64][260];
  __shared__ float xcs[64][260];
  __shared__ float cwl[1024];
  __shared__ float cbl[256];
  int t = threadIdx.x;
  int b = blockIdx.x;
  const float* src = xm + (size_t)b*16384;

  #pragma unroll
  for (int j=0;j<16;j++){
    int f4 = t + 256*j;
    int r = f4 >> 6, c4 = f4 & 63;
    *(float4*)&xms[r][c4*4] = ((const float4*)src)[f4];
  }
  *(float4*)&cwl[t*4] = ((const float4*)cw)[t];       // 256 channels x 4 taps
  if (t < 64) *(float4*)&cbl[t*4] = ((const float4*)cb)[t];
  __syncthreads();

  int c4 = t & 63; int c0 = c4*4;
  int sr = t >> 6;
  float4 wk[4];
  #pragma unroll
  for (int k=0;k<4;k++)
    wk[k] = make_float4(cwl[(c0+0)*4+k], cwl[(c0+1)*4+k], cwl[(c0+2)*4+k], cwl[(c0+3)*4+k]);
  float4 bias4 = *(float4*)&cbl[c0];
  for (int j=0;j<16;j++){
    int s = sr*16 + j;
    float4 a = bias4;
    #pragma unroll
    for (int k=0;k<4;k++){
      int sp = s - 3 + k;
      if (sp >= 0){
        float4 xv = *(const float4*)&xms[sp][c0];
        a.x += xv.x*wk[k].x; a.y += xv.y*wk[k].y; a.z += xv.z*wk[k].z; a.w += xv.w*wk[k].w;
      }
    }
    a.x = siluf(a.x); a.y = siluf(a.y); a.z = siluf(a.z); a.w = siluf(a.w);
    *(float4*)&xcs[s][c0] = a;
    *(float4*)(xc + (size_t)b*16384 + (size_t)s*256 + c0) = a;
  }
  __syncthreads();

  int s = t >> 2, p = t & 3;
  float gig[4] = {0.f,0.f,0.f,0.f}, gfg[4] = {0.f,0.f,0.f,0.f};
  for (int gi = p*192; gi < p*192+192; gi++){
    int which = gi >> 8;
    int idx = gi & 255;
    int nb = idx >> 2, o = idx & 3;
    float4 w = *(const float4*)(qkvw + which*1024 + nb*16 + o*4);
    const float* s2 = (which==2) ? &xms[s][nb*4] : &xcs[s][nb*4];
    float val = w.x*s2[0] + w.y*s2[1] + w.z*s2[2] + w.w*s2[3];
    float4 gw4 = *(const float4*)(igw + (size_t)gi*4);
    float4 fw4 = *(const float4*)(fgw + (size_t)gi*4);
    gig[0]+=val*gw4.x; gig[1]+=val*gw4.y; gig[2]+=val*gw4.z; gig[3]+=val*gw4.w;
    gfg[0]+=val*fw4.x; gfg[1]+=val*fw4.y; gfg[2]+=val*fw4.z; gfg[3]+=val*fw4.w;
  }
  #pragma unroll
  for (int m=0;m<4;m++){
    gig[m] += __shfl_xor(gig[m],1,4); gig[m] += __shfl_xor(gig[m],2,4);
    gfg[m] += __shfl_xor(gfg[m],1,4); gfg[m] += __shfl_xor(gfg[m],2,4);
  }
  if (p == 0){
    #pragma unroll
    for (int m=0;m<4;m++){
      ig[(size_t)b*256 + m*64 + s] = gig[m] + igb[m];
      fg[(size_t)b*256 + m*64 + s] = gfg[m] + fgb[m];
    }
  }
}

// ---------------- mLSTM attention per (b, head); writes head-LN'ed h into xm buffer ----------------
__global__ __launch_bounds__(256) void k_attn(
    float* __restrict__ xm, const float* __restrict__ xc,
    const float* __restrict__ qkvw,
    const float* __restrict__ igp, const float* __restrict__ fgp,
    const float* __restrict__ onorm)
{
  __shared__ float qs[64][68];
  __shared__ float ksm[64][68];
  __shared__ float vsm[64][68];
  __shared__ float xcl[64][68];
  __shared__ float xml[64][68];
  __shared__ float cnm[64][65];
  __shared__ float csum[65];
  __shared__ float pmax[64];
  __shared__ float igl[64];
  __shared__ float lfs[64];
  __shared__ float nrec[64];

  int t = threadIdx.x;
  int b = blockIdx.x >> 2, hh = blockIdx.x & 3;
  const float* xcb = xc + (size_t)b*16384 + hh*64;
  float* xmb = xm + (size_t)b*16384 + hh*64;

  #pragma unroll
  for (int j=0;j<4;j++){
    int u = t + 256*j;
    int r = u >> 4, q4 = u & 15;
    *(float4*)&xcl[r][q4*4] = *(const float4*)(xcb + (size_t)r*256 + q4*4);
    *(float4*)&xml[r][q4*4] = *(const float4*)(xmb + (size_t)r*256 + q4*4);
  }
  if (t < 64){
    lfs[t] = logsigf(fgp[(size_t)b*256 + hh*64 + t]);
    igl[t] = igp[(size_t)b*256 + hh*64 + t];
  }
  __syncthreads();
  if (t == 0){
    float cacc = 0.f, pm = -1e30f;
    csum[0] = 0.f;
    for (int s=0;s<64;s++){
      cacc += lfs[s];
      csum[s+1] = cacc;
      pm = fmaxf(pm, igl[s] - cacc);
      pmax[s] = pm;
    }
  }
  #pragma unroll
  for (int j=0;j<4;j++){
    int u = t + 256*j;
    int s = u >> 4, lb = u & 15;
    int nb = hh*16 + lb;
    const float* xq = &xcl[s][lb*4];
    const float* xv = &xml[s][lb*4];
    #pragma unroll
    for (int o=0;o<4;o++){
      float4 wq = *(const float4*)(qkvw + nb*16 + o*4);
      float4 wkk = *(const float4*)(qkvw + 1024 + nb*16 + o*4);
      float4 wv = *(const float4*)(qkvw + 2048 + nb*16 + o*4);
      qs[s][lb*4+o]  = wq.x*xq[0]+wq.y*xq[1]+wq.z*xq[2]+wq.w*xq[3];
      ksm[s][lb*4+o] = wkk.x*xq[0]+wkk.y*xq[1]+wkk.z*xq[2]+wkk.w*xq[3];
      vsm[s][lb*4+o] = wv.x*xv[0]+wv.y*xv[1]+wv.z*xv[2]+wv.w*xv[3];
    }
  }
  __syncthreads();

  int i = t >> 2;
  int jq = t & 3;
  float mi = csum[i+1] + pmax[i];
  float rs = 0.f;
  for (int jj=0;jj<16;jj++){
    int j = jq*16 + jj;
    if (j <= i){
      const float4* qa = (const float4*)&qs[i][0];
      const float4* ka = (const float4*)&ksm[j][0];
      float dp = 0.f;
      #pragma unroll
      for (int kk=0;kk<16;kk++){
        float4 a = qa[kk], c = ka[kk];
        dp += a.x*c.x + a.y*c.y + a.z*c.z + a.w*c.w;
      }
      float val = dp * 0.125f * __expf(csum[i+1] - csum[j+1] + igl[j] - mi);
      cnm[i][j] = val;
      rs += val;
    }
  }
  rs += __shfl_xor(rs, 1, 4);
  rs += __shfl_xor(rs, 2, 4);
  if (jq == 0){
    float nm = fmaxf(fabsf(rs), __expf(-mi));
    nrec[i] = 1.f/(nm + 1e-6f);
  }
  __syncthreads();

  int d0 = jq*16;
  float acc[16];
  #pragma unroll
  for (int q=0;q<16;q++) acc[q]=0.f;
  float nr = nrec[i];
  for (int j=0;j<=i;j++){
    float cwv = cnm[i][j] * nr;
    const float4* va = (const float4*)&vsm[j][d0];
    #pragma unroll
    for (int q=0;q<4;q++){
      float4 v4 = va[q];
      acc[q*4+0] += cwv*v4.x; acc[q*4+1] += cwv*v4.y; acc[q*4+2] += cwv*v4.z; acc[q*4+3] += cwv*v4.w;
    }
  }
  float su=0.f, sq=0.f;
  #pragma unroll
  for (int q=0;q<16;q++){ su += acc[q]; sq += acc[q]*acc[q]; }
  su += __shfl_xor(su,1,4); su += __shfl_xor(su,2,4);
  sq += __shfl_xor(sq,1,4); sq += __shfl_xor(sq,2,4);
  float mu = su*(1.f/64.f);
  float var = sq*(1.f/64.f) - mu*mu;
  float ivr = rsqrtf(var + 1e-5f);
  const float* onw = onorm + hh*64 + d0;
  #pragma unroll
  for (int q=0;q<4;q++){
    float4 o4;
    o4.x = (acc[q*4+0]-mu)*ivr*onw[q*4+0];
    o4.y = (acc[q*4+1]-mu)*ivr*onw[q*4+1];
    o4.z = (acc[q*4+2]-mu)*ivr*onw[q*4+2];
    o4.w = (acc[q*4+3]-mu)*ivr*onw[q*4+3];
    *(float4*)(xmb + (size_t)i*256 + d0 + q*4) = o4;
  }
}

// ---------------- mLSTM combine + down-projection + residual, LDS-staged weights ----------------
// 32 tokens/block, grid = 1024
__global__ __launch_bounds__(256) void k_comb_down(
    float* __restrict__ h, const float* __restrict__ hln,
    const float* __restrict__ xc, const float* __restrict__ z,
    const float* __restrict__ skip, const float* __restrict__ down)
{
  __shared__ float comb[32][260];
  __shared__ float bw[2][16][128];
  int t = threadIdx.x;
  size_t tok0 = (size_t)blockIdx.x*32;
  #pragma unroll
  for (int j=0;j<8;j++){
    int f4 = t + 256*j;
    int r = f4 >> 6, c4 = f4 & 63;
    size_t gi = (tok0 + r)*256 + c4*4;
    float4 a  = *(const float4*)(hln + gi);
    float4 xv = *(const float4*)(xc + gi);
    float4 zv = *(const float4*)(z + gi);
    float4 sk = *(const float4*)(skip + c4*4);
    float4 o;
    o.x = (a.x + sk.x*xv.x)*siluf(zv.x);
    o.y = (a.y + sk.y*xv.y)*siluf(zv.y);
    o.z = (a.z + sk.z*xv.z)*siluf(zv.z);
    o.w = (a.w + sk.w*xv.w)*siluf(zv.w);
    *(float4*)&comb[r][c4*4] = o;
  }

  float4 regs[2];
  auto stage = [&](int kc){
    #pragma unroll
    for (int j=0;j<2;j++){
      int idx = t + 256*j;
      int row = idx >> 5, c4 = idx & 31;
      regs[j] = *(const float4*)(down + (size_t)(kc*16+row)*128 + c4*4);
    }
  };
  auto wrt = [&](int buf){
    #pragma unroll
    for (int j=0;j<2;j++){
      int idx = t + 256*j;
      int row = idx >> 5, c4 = idx & 31;
      *(float4*)&bw[buf][row][c4*4] = regs[j];
    }
  };
  stage(0); wrt(0);
  __syncthreads();

  int r0 = (t >> 5) * 4;
  int c0 = (t & 31) * 4;
  float4 a2[4];
  #pragma unroll
  for (int i=0;i<4;i++) a2[i]=make_float4(0,0,0,0);
  for (int kc=0;kc<16;kc++){
    if (kc<15) stage(kc+1);
    int buf = kc & 1;
    #pragma unroll
    for (int k=0;k<16;k++){
      float4 wv = *(float4*)&bw[buf][k][c0];
      int kk = kc*16 + k;
      #pragma unroll
      for (int i=0;i<4;i++){
        float xv = comb[r0+i][kk];
        a2[i].x+=xv*wv.x; a2[i].y+=xv*wv.y; a2[i].z+=xv*wv.z; a2[i].w+=xv*wv.w;
      }
    }
    if (kc<15) wrt(buf^1);
    __syncthreads();
  }
  #pragma unroll
  for (int i=0;i<4;i++){
    float* dstp = h + (tok0 + r0 + i)*128 + c0;
    float4 hv = *(float4*)dstp;
    hv.x += a2[i].x; hv.y += a2[i].y; hv.z += a2[i].z; hv.w += a2[i].w;
    *(float4*)dstp = hv;
  }
}

// ---------------- final LN + head, LDS-staged weights ----------------
// 32 tokens/block, grid = 1024
__global__ __launch_bounds__(256) void k_head(
    const float* __restrict__ h, const float* __restrict__ lnw,
    const float* __restrict__ w, const float* __restrict__ bias2,
    float* __restrict__ out)
{
  __shared__ float xln[32][132];
  __shared__ float bws[2][16][256];
  __shared__ float red[32][8];
  __shared__ float red2[32][8];
  int t = threadIdx.x;
  size_t tok0 = (size_t)blockIdx.x * 32;

  ln_rows(h + tok0*128, lnw, &xln[0][0], 132, red, red2, t);
  __syncthreads();

  float4 regs[4];
  auto stage = [&](int kc){
    #pragma unroll
    for (int j=0;j<4;j++){
      int idx = t + 256*j;
      int row = idx >> 6, c4 = idx & 63;
      regs[j] = *(const float4*)(w + (size_t)(kc*16+row)*256 + c4*4);
    }
  };
  auto wrt = [&](int buf){
    #pragma unroll
    for (int j=0;j<4;j++){
      int idx = t + 256*j;
      int row = idx >> 6, c4 = idx & 63;
      *(float4*)&bws[buf][row][c4*4] = regs[j];
    }
  };
  stage(0); wrt(0);
  __syncthreads();

  int r0 = (t >> 5) * 4;
  int c0 = (t & 31) * 8;
  float4 a0[4], a1[4];
  #pragma unroll
  for (int i=0;i<4;i++){ a0[i]=make_float4(0,0,0,0); a1[i]=make_float4(0,0,0,0); }
  for (int kc=0;kc<8;kc++){
    if (kc<7) stage(kc+1);
    int buf = kc & 1;
    #pragma unroll
    for (int k=0;k<16;k++){
      float4 w0 = *(float4*)&bws[buf][k][c0];
      float4 w1 = *(float4*)&bws[buf][k][c0+4];
      int kk = kc*16 + k;
      #pragma unroll
      for (int i=0;i<4;i++){
        float xv = xln[r0+i][kk];
        a0[i].x+=xv*w0.x; a0[i].y+=xv*w0.y; a0[i].z+=xv*w0.z; a0[i].w+=xv*w0.w;
        a1[i].x+=xv*w1.x; a1[i].y+=xv*w1.y; a1[i].z+=xv*w1.z; a1[i].w+=xv*w1.w;
      }
    }
    if (kc<7) wrt(buf^1);
    __syncthreads();
  }
  float4 b0 = *(const float4*)(bias2 + c0);
  float4 b1 = *(const float4*)(bias2 + c0 + 4);
  #pragma unroll
  for (int i=0;i<4;i++){
    float* dstp = out + (tok0 + r0 + i)*256 + c0;
    float4 o0, o1;
    o0.x=a0[i].x+b0.x; o0.y=a0[i].y+b0.y; o0.z=a0[i].z+b0.z; o0.w=a0[i].w+b0.w;
    o1.x=a1[i].x+b1.x; o1.y=a1[i].y+b1.y; o1.z=a1[i].z+b1.z; o1.w=a1[i].w+b1.w;
    ((float4*)dstp)[0]=o0; ((float4*)dstp)[1]=o1;
  }
}

extern "C" void kernel_launch(void* const* d_in, const int* in_sizes, int n_in,
                              void* d_out, int out_size, void* d_ws, size_t ws_size,
                              hipStream_t stream)
{
  const int*   x      = (const int*)  d_in[0];
  const float* embed  = (const float*)d_in[1];
  const float* s_ln1  = (const float*)d_in[2];
  const float* s_gw   = (const float*)d_in[3];
  const float* s_rec  = (const float*)d_in[4];
  const float* s_bias = (const float*)d_in[5];
  const float* s_gn   = (const float*)d_in[6];
  const float* s_ln2  = (const float*)d_in[7];
  const float* s_ffu  = (const float*)d_in[8];
  const float* s_ffd  = (const float*)d_in[9];
  const float* m_ln1  = (const float*)d_in[10];
  const float* m_up   = (const float*)d_in[11];
  const float* m_cw   = (const float*)d_in[12];
  const float* m_cb   = (const float*)d_in[13];
  const float* m_qkv  = (const float*)d_in[14];
  const float* m_igw  = (const float*)d_in[15];
  const float* m_igb  = (const float*)d_in[16];
  const float* m_fgw  = (const float*)d_in[17];
  const float* m_fgb  = (const float*)d_in[18];
  const float* m_skip = (const float*)d_in[19];
  const float* m_onw  = (const float*)d_in[20];
  const float* m_down = (const float*)d_in[21];
  const float* m_ln2  = (const float*)d_in[22];
  const float* m_ffu  = (const float*)d_in[23];
  const float* m_ffd  = (const float*)d_in[24];
  const float* postln = (const float*)d_in[25];
  const float* headw  = (const float*)d_in[26];
  const float* headb  = (const float*)d_in[27];

  float* p = (float*)d_ws;
  float* hbuf = p; p += 4194304;                     // (B*S*D)
  size_t avail = ws_size / 4;
  const size_t need_full = 4194304ULL + 3ULL*8388608ULL + 2ULL*131072ULL;
  float* xmbuf;
  if (avail >= need_full){ xmbuf = p; p += 8388608; }
  else                   { xmbuf = (float*)d_out; }  // alias xm/h_ln into d_out if ws is small
  float* zbuf  = p; p += 8388608;
  float* xcbuf = p; p += 8388608;
  float* igbuf = p; p += 131072;
  float* fgbuf = p; p += 131072;

  k_embed<<<4096, 256, 0, stream>>>(x, embed, hbuf);

  for (int i=0;i<2;i++){
    k_slstm<<<512, 512, 0, stream>>>(hbuf, s_ln1+i*128, s_gw+i*16384, s_rec+i*16384,
                                     s_bias+i*512, s_gn+i*128);
    k_ffn<<<1024, 256, 0, stream>>>(hbuf, s_ln2+i*128, s_ffu+i*32768, s_ffd+i*16384);
    k_up<<<2048, 256, 0, stream>>>(hbuf, m_ln1+i*128, m_up+i*65536, xmbuf, zbuf);
    k_convgates<<<512, 256, 0, stream>>>(xmbuf, xcbuf, m_cw+i*1024, m_cb+i*256, m_qkv+i*3072,
                                         m_igw+i*3072, m_igb+i*4, m_fgw+i*3072, m_fgb+i*4,
                                         igbuf, fgbuf);
    k_attn<<<2048, 256, 0, stream>>>(xmbuf, xcbuf, m_qkv+i*3072, igbuf, fgbuf, m_onw+i*256);
    k_comb_down<<<1024, 256, 0, stream>>>(hbuf, xmbuf, xcbuf, zbuf, m_skip+i*256, m_down+i*32768);
    k_ffn<<<1024, 256, 0, stream>>>(hbuf, m_ln2+i*128, m_ffu+i*32768, m_ffd+i*16384);
  }

  k_head<<<1024, 256, 0, stream>>>(hbuf, postln, headw, headb, (float*)d_out);
}

// Round 6
// 1348.641 us; speedup vs baseline: 1.8281x; 1.1272x over previous
//
#include <hip/hip_runtime.h>
#include <math.h>

// B=512 S=64 D=128 V=256 NH=4 HD=32 INNER=256 NHM=4 DHM=64 BS=4 NB=64 K=4 FF=128

__device__ __forceinline__ float sigf(float x){ return 1.f/(1.f+__expf(-x)); }
__device__ __forceinline__ float siluf(float x){ return x/(1.f+__expf(-x)); }
__device__ __forceinline__ float logsigf(float x){ return fminf(x,0.f) - log1pf(__expf(-fabsf(x))); }
__device__ __forceinline__ float geluf(float x){
  return 0.5f*x*(1.f+tanhf(0.7978845608028654f*(x+0.044715f*x*x*x)));
}
__device__ __forceinline__ void sums4(float4 v, float& s, float& q){
  s += v.x+v.y+v.z+v.w;
  q += v.x*v.x+v.y*v.y+v.z*v.z+v.w*v.w;
}

// LayerNorm rows of 128; 8 threads per row; dst[r*dstride+c] = (x-mu)*rsqrt(var+eps)*w[c]
__device__ __forceinline__ void ln_rows(const float* __restrict__ src, const float* __restrict__ lnw,
                                        float* __restrict__ dst, int dstride,
                                        float (*red)[8], float (*red2)[8], int t)
{
  int r = t >> 3, l8 = t & 7;
  const float4* s4 = (const float4*)(src + (size_t)r*128 + l8*16);
  float4 v0=s4[0], v1=s4[1], v2=s4[2], v3=s4[3];
  float su=0.f, sq=0.f;
  sums4(v0,su,sq); sums4(v1,su,sq); sums4(v2,su,sq); sums4(v3,su,sq);
  red[r][l8]=su; red2[r][l8]=sq;
  __syncthreads();
  float ts=0.f, tq=0.f;
  #pragma unroll
  for (int k=0;k<8;k++){ ts+=red[r][k]; tq+=red2[r][k]; }
  float mu = ts*(1.f/128.f);
  float var = tq*(1.f/128.f) - mu*mu;
  float iv = rsqrtf(var+1e-5f);
  int c0 = l8*16;
  float vv[16];
  *(float4*)&vv[0]=v0; *(float4*)&vv[4]=v1; *(float4*)&vv[8]=v2; *(float4*)&vv[12]=v3;
  #pragma unroll
  for (int q2=0;q2<16;q2++) dst[r*dstride + c0 + q2] = (vv[q2]-mu)*iv*lnw[c0+q2];
}

// ---------------- embed ----------------
__global__ __launch_bounds__(256) void k_embed(const int* __restrict__ x, const float* __restrict__ embed,
                                               float* __restrict__ h)
{
  int idx4 = blockIdx.x*256 + threadIdx.x;      // over B*S*D/4 = 1048576 float4
  int tok = idx4 >> 5;
  int c4  = idx4 & 31;
  int id = x[tok];
  reinterpret_cast<float4*>(h)[idx4] = reinterpret_cast<const float4*>(embed)[id*32 + c4];
}

// ---------------- fold qkv blockdiag into gate weights: wtab[l][4][256][4] ----------------
// tab 0: ig from xc, 1: ig from xm, 2: fg from xc, 3: fg from xm
__global__ __launch_bounds__(512) void k_prep(
    const float* __restrict__ qkvw,  // [2][3][64][4][4]
    const float* __restrict__ igw,   // [2][768][4]
    const float* __restrict__ fgw,   // [2][768][4]
    float* __restrict__ wtab)        // [2][4][256][4]
{
  int t = threadIdx.x;               // 512
  int l = t >> 8, c = t & 255;
  int nb = c >> 2, i = c & 3;
  const float* qk  = qkvw + l*3072;
  const float* igl = igw + l*3072;
  const float* fgl = fgw + l*3072;
  float igc[4]={0,0,0,0}, igm[4]={0,0,0,0}, fgc[4]={0,0,0,0}, fgm[4]={0,0,0,0};
  #pragma unroll
  for (int o=0;o<4;o++){
    float wq = qk[nb*16 + o*4 + i];
    float wk = qk[1024 + nb*16 + o*4 + i];
    float wv = qk[2048 + nb*16 + o*4 + i];
    int no = nb*4+o;
    #pragma unroll
    for (int m=0;m<4;m++){
      igc[m] += wq*igl[no*4+m] + wk*igl[(256+no)*4+m];
      igm[m] += wv*igl[(512+no)*4+m];
      fgc[m] += wq*fgl[no*4+m] + wk*fgl[(256+no)*4+m];
      fgm[m] += wv*fgl[(512+no)*4+m];
    }
  }
  float* dst = wtab + l*4096;
  #pragma unroll
  for (int m=0;m<4;m++){
    dst[(0*256+c)*4+m] = igc[m];
    dst[(1*256+c)*4+m] = igm[m];
    dst[(2*256+c)*4+m] = fgc[m];
    dst[(3*256+c)*4+m] = fgm[m];
  }
}

// ---------------- sLSTM (fused LN + scan + head-LN + residual) ----------------
__global__ __launch_bounds__(512) void k_slstm(
    float* __restrict__ h, const float* __restrict__ lnw,
    const float* __restrict__ gw, const float* __restrict__ rw,
    const float* __restrict__ bias, const float* __restrict__ gn)
{
  __shared__ float xh[64][128];     // LN-ed input, overwritten per-step with y
  __shared__ float hb[128];
  __shared__ float raw[512];
  __shared__ float red[64][8];
  __shared__ float red2[64][8];
  __shared__ float mu_s[64][4];
  __shared__ float iv_s[64][4];

  int t = threadIdx.x;
  int b = blockIdx.x;
  float* hrow = h + (size_t)b*8192;

  ln_rows(hrow, lnw, &xh[0][0], 128, red, red2, t);
  __syncthreads();

  int g  = t >> 7;
  int nh = (t >> 5) & 3;
  int e  = t & 31;
  float wg[32], wr[32];
  {
    const float4* g4 = (const float4*)(gw + (((g*4+nh)*32+e)*32));
    const float4* r4 = (const float4*)(rw + (((g*4+nh)*32+e)*32));
    #pragma unroll
    for (int q=0;q<8;q++){
      float4 a=g4[q]; wg[4*q]=a.x; wg[4*q+1]=a.y; wg[4*q+2]=a.z; wg[4*q+3]=a.w;
      float4 c=r4[q]; wr[4*q]=c.x; wr[4*q+1]=c.y; wr[4*q+2]=c.z; wr[4*q+3]=c.w;
    }
  }
  float bs = bias[(g*4+nh)*32+e];
  float c_s=0.f, n_s=0.f, m_s=0.f;
  if (t<128) hb[t]=0.f;
  __syncthreads();

  for (int s=0;s<64;s++){
    const float4* xr = (const float4*)&xh[s][nh*32];
    const float4* hr = (const float4*)&hb[nh*32];
    float acc = bs;
    #pragma unroll
    for (int q=0;q<8;q++){
      float4 xv = xr[q]; float4 hv = hr[q];
      acc += xv.x*wg[4*q+0] + xv.y*wg[4*q+1] + xv.z*wg[4*q+2] + xv.w*wg[4*q+3];
      acc += hv.x*wr[4*q+0] + hv.y*wr[4*q+1] + hv.z*wr[4*q+2] + hv.w*wr[4*q+3];
    }
    raw[t] = acc;
    __syncthreads();
    if (t < 128){
      float i_r = raw[t], f_r = raw[128+t], z_r = raw[256+t], o_r = raw[384+t];
      float lf = m_s + logsigf(f_r);
      float mn = fmaxf(i_r, lf);
      float iv = __expf(i_r-mn), fv = __expf(lf-mn);
      c_s = fv*c_s + iv*tanhf(z_r);
      n_s = fv*n_s + iv;
      m_s = mn;
      float hn = sigf(o_r)*c_s/n_s;
      hb[t] = hn;
      xh[s][t] = hn;
    }
    __syncthreads();
  }

  if (t < 256){
    int s = t>>2, n = t&3;
    const float4* yr = (const float4*)&xh[s][n*32];
    float su=0.f, sq=0.f;
    #pragma unroll
    for (int q=0;q<8;q++){ float4 v = yr[q]; sums4(v,su,sq); }
    float mu = su*(1.f/32.f);
    float var = sq*(1.f/32.f) - mu*mu;
    mu_s[s][n]=mu; iv_s[s][n]=rsqrtf(var+1e-5f);
  }
  __syncthreads();
  #pragma unroll
  for (int rr=0; rr<16; rr++){
    int idx = t + 512*rr;
    int s = idx>>7, c = idx&127;
    float y = (xh[s][c] - mu_s[s][c>>5]) * iv_s[s][c>>5] * gn[c];
    hrow[idx] += y;
  }
}

// ---------------- FFN (fused LN + up/gelu-gate + down + residual), LDS-staged weights ----------------
// 32 tokens/block, grid = 1024
__global__ __launch_bounds__(256) void k_ffn(
    float* __restrict__ h, const float* __restrict__ lnw,
    const float* __restrict__ up, const float* __restrict__ down)
{
  __shared__ float xln[32][132];
  __shared__ float hid[32][132];
  __shared__ float bws[2][16][256];
  __shared__ float red[32][8];
  __shared__ float red2[32][8];
  int t = threadIdx.x;
  size_t tok0 = (size_t)blockIdx.x * 32;

  ln_rows(h + tok0*128, lnw, &xln[0][0], 132, red, red2, t);
  __syncthreads();

  int r0 = (t >> 5) * 4;      // 4 rows
  int c0 = (t & 31) * 4;      // 4 cols (of 128)

  // ---- GEMM1: xln(32x128) @ up(128x256) -> gelu(g)*u -> hid(32x128)
  {
    float4 regs[4];
    auto stage = [&](int kc){
      #pragma unroll
      for (int j=0;j<4;j++){
        int idx = t + 256*j;
        int row = idx >> 6, c4 = idx & 63;
        regs[j] = *(const float4*)(up + (size_t)(kc*16+row)*256 + c4*4);
      }
    };
    auto wrt = [&](int buf){
      #pragma unroll
      for (int j=0;j<4;j++){
        int idx = t + 256*j;
        int row = idx >> 6, c4 = idx & 63;
        *(float4*)&bws[buf][row][c4*4] = regs[j];
      }
    };
    stage(0); wrt(0);
    __syncthreads();
    float4 ag[4], au[4];
    #pragma unroll
    for (int i=0;i<4;i++){ ag[i]=make_float4(0,0,0,0); au[i]=make_float4(0,0,0,0); }
    for (int kc=0;kc<8;kc++){
      if (kc<7) stage(kc+1);
      int buf = kc & 1;
      #pragma unroll
      for (int k=0;k<16;k++){
        float4 wg = *(float4*)&bws[buf][k][c0];
        float4 wu = *(float4*)&bws[buf][k][c0+128];
        int kk = kc*16 + k;
        #pragma unroll
        for (int i=0;i<4;i++){
          float xv = xln[r0+i][kk];
          ag[i].x+=xv*wg.x; ag[i].y+=xv*wg.y; ag[i].z+=xv*wg.z; ag[i].w+=xv*wg.w;
          au[i].x+=xv*wu.x; au[i].y+=xv*wu.y; au[i].z+=xv*wu.z; au[i].w+=xv*wu.w;
        }
      }
      if (kc<7) wrt(buf^1);
      __syncthreads();
    }
    #pragma unroll
    for (int i=0;i<4;i++){
      hid[r0+i][c0+0] = geluf(ag[i].x)*au[i].x;
      hid[r0+i][c0+1] = geluf(ag[i].y)*au[i].y;
      hid[r0+i][c0+2] = geluf(ag[i].z)*au[i].z;
      hid[r0+i][c0+3] = geluf(ag[i].w)*au[i].w;
    }
  }
  __syncthreads();

  // ---- GEMM2: hid(32x128) @ down(128x128) -> += h
  {
    float (*bw2)[16][128] = (float (*)[16][128])bws;
    float4 regs[2];
    auto stage = [&](int kc){
      #pragma unroll
      for (int j=0;j<2;j++){
        int idx = t + 256*j;
        int row = idx >> 5, c4 = idx & 31;
        regs[j] = *(const float4*)(down + (size_t)(kc*16+row)*128 + c4*4);
      }
    };
    auto wrt = [&](int buf){
      #pragma unroll
      for (int j=0;j<2;j++){
        int idx = t + 256*j;
        int row = idx >> 5, c4 = idx & 31;
        *(float4*)&bw2[buf][row][c4*4] = regs[j];
      }
    };
    stage(0); wrt(0);
    __syncthreads();
    float4 a2[4];
    #pragma unroll
    for (int i=0;i<4;i++) a2[i]=make_float4(0,0,0,0);
    for (int kc=0;kc<8;kc++){
      if (kc<7) stage(kc+1);
      int buf = kc & 1;
      #pragma unroll
      for (int k=0;k<16;k++){
        float4 wv = *(float4*)&bw2[buf][k][c0];
        int kk = kc*16 + k;
        #pragma unroll
        for (int i=0;i<4;i++){
          float xv = hid[r0+i][kk];
          a2[i].x+=xv*wv.x; a2[i].y+=xv*wv.y; a2[i].z+=xv*wv.z; a2[i].w+=xv*wv.w;
        }
      }
      if (kc<7) wrt(buf^1);
      __syncthreads();
    }
    #pragma unroll
    for (int i=0;i<4;i++){
      float* dstp = h + (tok0 + r0 + i)*128 + c0;
      float4 hv = *(float4*)dstp;
      hv.x += a2[i].x; hv.y += a2[i].y; hv.z += a2[i].z; hv.w += a2[i].w;
      *(float4*)dstp = hv;
    }
  }
}

// ---------------- mLSTM up-projection (LN + 128->512), LDS-staged weights ----------------
// 64 tokens x 128 cols per block; grid = 512*4
__global__ __launch_bounds__(256) void k_up(
    const float* __restrict__ h, const float* __restrict__ lnw,
    const float* __restrict__ up, float* __restrict__ xm, float* __restrict__ z)
{
  __shared__ float xln[64][132];
  __shared__ float bw[2][32][128];
  __shared__ float red[64][4];
  __shared__ float red2[64][4];
  int t = threadIdx.x;
  int mt = blockIdx.x >> 2, nt = blockIdx.x & 3;
  size_t tok0 = (size_t)mt * 64;
  int n0 = nt * 128;

  // LN: 64 rows, 4 threads/row (32 cols each)
  {
    int r = t >> 2, l = t & 3;
    const float4* s4 = (const float4*)(h + (tok0 + (size_t)r)*128 + l*32);
    float4 v[8];
    float su=0.f, sq=0.f;
    #pragma unroll
    for (int q=0;q<8;q++){ v[q]=s4[q]; sums4(v[q],su,sq); }
    red[r][l]=su; red2[r][l]=sq;
    __syncthreads();
    float ts=red[r][0]+red[r][1]+red[r][2]+red[r][3];
    float tq=red2[r][0]+red2[r][1]+red2[r][2]+red2[r][3];
    float mu=ts*(1.f/128.f);
    float var=tq*(1.f/128.f)-mu*mu;
    float iv=rsqrtf(var+1e-5f);
    int cb=l*32;
    #pragma unroll
    for (int q=0;q<8;q++){
      xln[r][cb+q*4+0]=(v[q].x-mu)*iv*lnw[cb+q*4+0];
      xln[r][cb+q*4+1]=(v[q].y-mu)*iv*lnw[cb+q*4+1];
      xln[r][cb+q*4+2]=(v[q].z-mu)*iv*lnw[cb+q*4+2];
      xln[r][cb+q*4+3]=(v[q].w-mu)*iv*lnw[cb+q*4+3];
    }
  }

  float4 regs[4];
  auto stage = [&](int kc){
    #pragma unroll
    for (int j=0;j<4;j++){
      int idx = t + 256*j;
      int row = idx >> 5, c4 = idx & 31;
      regs[j] = *(const float4*)(up + (size_t)(kc*32+row)*512 + n0 + c4*4);
    }
  };
  auto wrt = [&](int buf){
    #pragma unroll
    for (int j=0;j<4;j++){
      int idx = t + 256*j;
      int row = idx >> 5, c4 = idx & 31;
      *(float4*)&bw[buf][row][c4*4] = regs[j];
    }
  };
  stage(0); wrt(0);
  __syncthreads();

  int r0 = (t >> 5) * 8;      // 8 rows
  int c0 = (t & 31) * 4;      // 4 cols (of 128)
  float4 acc4[8];
  #pragma unroll
  for (int i=0;i<8;i++) acc4[i]=make_float4(0,0,0,0);

  for (int kc=0;kc<4;kc++){
    if (kc<3) stage(kc+1);
    int buf = kc & 1;
    #pragma unroll 8
    for (int k=0;k<32;k++){
      float4 wv = *(float4*)&bw[buf][k][c0];
      int kk = kc*32 + k;
      #pragma unroll
      for (int i=0;i<8;i++){
        float xv = xln[r0+i][kk];
        acc4[i].x += xv*wv.x; acc4[i].y += xv*wv.y; acc4[i].z += xv*wv.z; acc4[i].w += xv*wv.w;
      }
    }
    if (kc<3) wrt(buf^1);
    __syncthreads();
  }

  float* dst; int cbase;
  if (n0 < 256){ dst = xm; cbase = n0 + c0; }
  else         { dst = z;  cbase = n0 - 256 + c0; }
  #pragma unroll
  for (int i=0;i<8;i++)
    *(float4*)(dst + (tok0 + r0 + i)*256 + cbase) = acc4[i];
}

// ---------------- mLSTM conv + silu + folded gate projections (no LDS) ----------------
// one block per b, 256 threads: (sr 0..3) x (c4 0..63); rolling conv window in regs
__global__ __launch_bounds__(256) void k_convgates(
    const float* __restrict__ xm, float* __restrict__ xc,
    const float* __restrict__ cw, const float* __restrict__ cb,
    const float* __restrict__ wtab,
    const float* __restrict__ igb, const float* __restrict__ fgb,
    float* __restrict__ ig, float* __restrict__ fg)
{
  int t = threadIdx.x;
  int b = blockIdx.x;
  int c4 = t & 63, sr = t >> 6;
  int c0 = c4*4;
  const float* src = xm + (size_t)b*16384;
  float* dstc = xc + (size_t)b*16384;

  // conv weights for my 4 channels (cw is [256][4], transpose into per-tap float4)
  float4 r0 = *(const float4*)(cw + (c0+0)*4);
  float4 r1 = *(const float4*)(cw + (c0+1)*4);
  float4 r2 = *(const float4*)(cw + (c0+2)*4);
  float4 r3 = *(const float4*)(cw + (c0+3)*4);
  float4 wk0 = make_float4(r0.x, r1.x, r2.x, r3.x);
  float4 wk1 = make_float4(r0.y, r1.y, r2.y, r3.y);
  float4 wk2 = make_float4(r0.z, r1.z, r2.z, r3.z);
  float4 wk3 = make_float4(r0.w, r1.w, r2.w, r3.w);
  float4 bias4 = *(const float4*)(cb + c0);

  // folded gate tables for my 4 channels
  float4 Wigc[4], Wigm[4], Wfgc[4], Wfgm[4];
  #pragma unroll
  for (int i=0;i<4;i++){
    Wigc[i] = *(const float4*)(wtab + (0*256+c0+i)*4);
    Wigm[i] = *(const float4*)(wtab + (1*256+c0+i)*4);
    Wfgc[i] = *(const float4*)(wtab + (2*256+c0+i)*4);
    Wfgm[i] = *(const float4*)(wtab + (3*256+c0+i)*4);
  }

  int s0 = sr*16;
  float4 w0 = make_float4(0,0,0,0), w1 = w0, w2 = w0;
  if (s0 >= 3){
    w0 = *(const float4*)(src + (size_t)(s0-3)*256 + c0);
    w1 = *(const float4*)(src + (size_t)(s0-2)*256 + c0);
    w2 = *(const float4*)(src + (size_t)(s0-1)*256 + c0);
  }

  for (int j=0;j<16;j++){
    int s = s0 + j;
    float4 w3 = *(const float4*)(src + (size_t)s*256 + c0);
    float4 a;
    a.x = bias4.x + w0.x*wk0.x + w1.x*wk1.x + w2.x*wk2.x + w3.x*wk3.x;
    a.y = bias4.y + w0.y*wk0.y + w1.y*wk1.y + w2.y*wk2.y + w3.y*wk3.y;
    a.z = bias4.z + w0.z*wk0.z + w1.z*wk1.z + w2.z*wk2.z + w3.z*wk3.z;
    a.w = bias4.w + w0.w*wk0.w + w1.w*wk1.w + w2.w*wk2.w + w3.w*wk3.w;
    a.x = siluf(a.x); a.y = siluf(a.y); a.z = siluf(a.z); a.w = siluf(a.w);
    *(float4*)(dstc + (size_t)s*256 + c0) = a;

    float pig[4] = {0.f,0.f,0.f,0.f};
    float pfg[4] = {0.f,0.f,0.f,0.f};
    const float xcv[4] = {a.x,a.y,a.z,a.w};
    const float xmv[4] = {w3.x,w3.y,w3.z,w3.w};
    #pragma unroll
    for (int i=0;i<4;i++){
      pig[0] += xcv[i]*Wigc[i].x + xmv[i]*Wigm[i].x;
      pig[1] += xcv[i]*Wigc[i].y + xmv[i]*Wigm[i].y;
      pig[2] += xcv[i]*Wigc[i].z + xmv[i]*Wigm[i].z;
      pig[3] += xcv[i]*Wigc[i].w + xmv[i]*Wigm[i].w;
      pfg[0] += xcv[i]*Wfgc[i].x + xmv[i]*Wfgm[i].x;
      pfg[1] += xcv[i]*Wfgc[i].y + xmv[i]*Wfgm[i].y;
      pfg[2] += xcv[i]*Wfgc[i].z + xmv[i]*Wfgm[i].z;
      pfg[3] += xcv[i]*Wfgc[i].w + xmv[i]*Wfgm[i].w;
    }
    #pragma unroll
    for (int off=32; off>=1; off>>=1){
      #pragma unroll
      for (int m=0;m<4;m++){
        pig[m] += __shfl_xor(pig[m], off, 64);
        pfg[m] += __shfl_xor(pfg[m], off, 64);
      }
    }
    if (c4 == 0){
      #pragma unroll
      for (int m=0;m<4;m++){
        ig[(size_t)b*256 + m*64 + s] = pig[m] + igb[m];
        fg[(size_t)b*256 + m*64 + s] = pfg[m] + fgb[m];
      }
    }
    w0=w1; w1=w2; w2=w3;
  }
}

// ---------------- mLSTM attention per (b, head); writes head-LN'ed h into xm buffer ----------------
__global__ __launch_bounds__(256) void k_attn(
    float* __restrict__ xm, const float* __restrict__ xc,
    const float* __restrict__ qkvw,
    const float* __restrict__ igp, const float* __restrict__ fgp,
    const float* __restrict__ onorm)
{
  __shared__ float qs[64][68];
  __shared__ float ksm[64][68];
  __shared__ float vsm[64][68];
  __shared__ float xcl[64][68];
  __shared__ float xml[64][68];
  __shared__ float cnm[64][65];
  __shared__ float csum[65];
  __shared__ float pmax[64];
  __shared__ float igl[64];
  __shared__ float lfs[64];
  __shared__ float nrec[64];

  int t = threadIdx.x;
  int b = blockIdx.x >> 2, hh = blockIdx.x & 3;
  const float* xcb = xc + (size_t)b*16384 + hh*64;
  float* xmb = xm + (size_t)b*16384 + hh*64;

  #pragma unroll
  for (int j=0;j<4;j++){
    int u = t + 256*j;
    int r = u >> 4, q4 = u & 15;
    *(float4*)&xcl[r][q4*4] = *(const float4*)(xcb + (size_t)r*256 + q4*4);
    *(float4*)&xml[r][q4*4] = *(const float4*)(xmb + (size_t)r*256 + q4*4);
  }
  if (t < 64){
    lfs[t] = logsigf(fgp[(size_t)b*256 + hh*64 + t]);
    igl[t] = igp[(size_t)b*256 + hh*64 + t];
  }
  __syncthreads();
  if (t == 0){
    float cacc = 0.f, pm = -1e30f;
    csum[0] = 0.f;
    for (int s=0;s<64;s++){
      cacc += lfs[s];
      csum[s+1] = cacc;
      pm = fmaxf(pm, igl[s] - cacc);
      pmax[s] = pm;
    }
  }
  #pragma unroll
  for (int j=0;j<4;j++){
    int u = t + 256*j;
    int s = u >> 4, lb = u & 15;
    int nb = hh*16 + lb;
    const float* xq = &xcl[s][lb*4];
    const float* xv = &xml[s][lb*4];
    #pragma unroll
    for (int o=0;o<4;o++){
      float4 wq = *(const float4*)(qkvw + nb*16 + o*4);
      float4 wkk = *(const float4*)(qkvw + 1024 + nb*16 + o*4);
      float4 wv = *(const float4*)(qkvw + 2048 + nb*16 + o*4);
      qs[s][lb*4+o]  = wq.x*xq[0]+wq.y*xq[1]+wq.z*xq[2]+wq.w*xq[3];
      ksm[s][lb*4+o] = wkk.x*xq[0]+wkk.y*xq[1]+wkk.z*xq[2]+wkk.w*xq[3];
      vsm[s][lb*4+o] = wv.x*xv[0]+wv.y*xv[1]+wv.z*xv[2]+wv.w*xv[3];
    }
  }
  __syncthreads();

  int i = t >> 2;
  int jq = t & 3;
  float mi = csum[i+1] + pmax[i];
  float rs = 0.f;
  for (int jj=0;jj<16;jj++){
    int j = jq*16 + jj;
    if (j <= i){
      const float4* qa = (const float4*)&qs[i][0];
      const float4* ka = (const float4*)&ksm[j][0];
      float dp = 0.f;
      #pragma unroll
      for (int kk=0;kk<16;kk++){
        float4 a = qa[kk], c = ka[kk];
        dp += a.x*c.x + a.y*c.y + a.z*c.z + a.w*c.w;
      }
      float val = dp * 0.125f * __expf(csum[i+1] - csum[j+1] + igl[j] - mi);
      cnm[i][j] = val;
      rs += val;
    }
  }
  rs += __shfl_xor(rs, 1, 4);
  rs += __shfl_xor(rs, 2, 4);
  if (jq == 0){
    float nm = fmaxf(fabsf(rs), __expf(-mi));
    nrec[i] = 1.f/(nm + 1e-6f);
  }
  __syncthreads();

  int d0 = jq*16;
  float acc[16];
  #pragma unroll
  for (int q=0;q<16;q++) acc[q]=0.f;
  float nr = nrec[i];
  for (int j=0;j<=i;j++){
    float cwv = cnm[i][j] * nr;
    const float4* va = (const float4*)&vsm[j][d0];
    #pragma unroll
    for (int q=0;q<4;q++){
      float4 v4 = va[q];
      acc[q*4+0] += cwv*v4.x; acc[q*4+1] += cwv*v4.y; acc[q*4+2] += cwv*v4.z; acc[q*4+3] += cwv*v4.w;
    }
  }
  float su=0.f, sq=0.f;
  #pragma unroll
  for (int q=0;q<16;q++){ su += acc[q]; sq += acc[q]*acc[q]; }
  su += __shfl_xor(su,1,4); su += __shfl_xor(su,2,4);
  sq += __shfl_xor(sq,1,4); sq += __shfl_xor(sq,2,4);
  float mu = su*(1.f/64.f);
  float var = sq*(1.f/64.f) - mu*mu;
  float ivr = rsqrtf(var + 1e-5f);
  const float* onw = onorm + hh*64 + d0;
  #pragma unroll
  for (int q=0;q<4;q++){
    float4 o4;
    o4.x = (acc[q*4+0]-mu)*ivr*onw[q*4+0];
    o4.y = (acc[q*4+1]-mu)*ivr*onw[q*4+1];
    o4.z = (acc[q*4+2]-mu)*ivr*onw[q*4+2];
    o4.w = (acc[q*4+3]-mu)*ivr*onw[q*4+3];
    *(float4*)(xmb + (size_t)i*256 + d0 + q*4) = o4;
  }
}

// ---------------- mLSTM combine + down-projection + residual, LDS-staged weights ----------------
// 32 tokens/block, grid = 1024
__global__ __launch_bounds__(256) void k_comb_down(
    float* __restrict__ h, const float* __restrict__ hln,
    const float* __restrict__ xc, const float* __restrict__ z,
    const float* __restrict__ skip, const float* __restrict__ down)
{
  __shared__ float comb[32][260];
  __shared__ float bw[2][16][128];
  int t = threadIdx.x;
  size_t tok0 = (size_t)blockIdx.x*32;
  #pragma unroll
  for (int j=0;j<8;j++){
    int f4 = t + 256*j;
    int r = f4 >> 6, c4 = f4 & 63;
    size_t gi = (tok0 + r)*256 + c4*4;
    float4 a  = *(const float4*)(hln + gi);
    float4 xv = *(const float4*)(xc + gi);
    float4 zv = *(const float4*)(z + gi);
    float4 sk = *(const float4*)(skip + c4*4);
    float4 o;
    o.x = (a.x + sk.x*xv.x)*siluf(zv.x);
    o.y = (a.y + sk.y*xv.y)*siluf(zv.y);
    o.z = (a.z + sk.z*xv.z)*siluf(zv.z);
    o.w = (a.w + sk.w*xv.w)*siluf(zv.w);
    *(float4*)&comb[r][c4*4] = o;
  }

  float4 regs[2];
  auto stage = [&](int kc){
    #pragma unroll
    for (int j=0;j<2;j++){
      int idx = t + 256*j;
      int row = idx >> 5, c4 = idx & 31;
      regs[j] = *(const float4*)(down + (size_t)(kc*16+row)*128 + c4*4);
    }
  };
  auto wrt = [&](int buf){
    #pragma unroll
    for (int j=0;j<2;j++){
      int idx = t + 256*j;
      int row = idx >> 5, c4 = idx & 31;
      *(float4*)&bw[buf][row][c4*4] = regs[j];
    }
  };
  stage(0); wrt(0);
  __syncthreads();

  int r0 = (t >> 5) * 4;
  int c0 = (t & 31) * 4;
  float4 a2[4];
  #pragma unroll
  for (int i=0;i<4;i++) a2[i]=make_float4(0,0,0,0);
  for (int kc=0;kc<16;kc++){
    if (kc<15) stage(kc+1);
    int buf = kc & 1;
    #pragma unroll
    for (int k=0;k<16;k++){
      float4 wv = *(float4*)&bw[buf][k][c0];
      int kk = kc*16 + k;
      #pragma unroll
      for (int i=0;i<4;i++){
        float xv = comb[r0+i][kk];
        a2[i].x+=xv*wv.x; a2[i].y+=xv*wv.y; a2[i].z+=xv*wv.z; a2[i].w+=xv*wv.w;
      }
    }
    if (kc<15) wrt(buf^1);
    __syncthreads();
  }
  #pragma unroll
  for (int i=0;i<4;i++){
    float* dstp = h + (tok0 + r0 + i)*128 + c0;
    float4 hv = *(float4*)dstp;
    hv.x += a2[i].x; hv.y += a2[i].y; hv.z += a2[i].z; hv.w += a2[i].w;
    *(float4*)dstp = hv;
  }
}

// ---------------- final LN + head, LDS-staged weights ----------------
// 32 tokens/block, grid = 1024
__global__ __launch_bounds__(256) void k_head(
    const float* __restrict__ h, const float* __restrict__ lnw,
    const float* __restrict__ w, const float* __restrict__ bias2,
    float* __restrict__ out)
{
  __shared__ float xln[32][132];
  __shared__ float bws[2][16][256];
  __shared__ float red[32][8];
  __shared__ float red2[32][8];
  int t = threadIdx.x;
  size_t tok0 = (size_t)blockIdx.x * 32;

  ln_rows(h + tok0*128, lnw, &xln[0][0], 132, red, red2, t);
  __syncthreads();

  float4 regs[4];
  auto stage = [&](int kc){
    #pragma unroll
    for (int j=0;j<4;j++){
      int idx = t + 256*j;
      int row = idx >> 6, c4 = idx & 63;
      regs[j] = *(const float4*)(w + (size_t)(kc*16+row)*256 + c4*4);
    }
  };
  auto wrt = [&](int buf){
    #pragma unroll
    for (int j=0;j<4;j++){
      int idx = t + 256*j;
      int row = idx >> 6, c4 = idx & 63;
      *(float4*)&bws[buf][row][c4*4] = regs[j];
    }
  };
  stage(0); wrt(0);
  __syncthreads();

  int r0 = (t >> 5) * 4;
  int c0 = (t & 31) * 8;
  float4 a0[4], a1[4];
  #pragma unroll
  for (int i=0;i<4;i++){ a0[i]=make_float4(0,0,0,0); a1[i]=make_float4(0,0,0,0); }
  for (int kc=0;kc<8;kc++){
    if (kc<7) stage(kc+1);
    int buf = kc & 1;
    #pragma unroll
    for (int k=0;k<16;k++){
      float4 w0 = *(float4*)&bws[buf][k][c0];
      float4 w1 = *(float4*)&bws[buf][k][c0+4];
      int kk = kc*16 + k;
      #pragma unroll
      for (int i=0;i<4;i++){
        float xv = xln[r0+i][kk];
        a0[i].x+=xv*w0.x; a0[i].y+=xv*w0.y; a0[i].z+=xv*w0.z; a0[i].w+=xv*w0.w;
        a1[i].x+=xv*w1.x; a1[i].y+=xv*w1.y; a1[i].z+=xv*w1.z; a1[i].w+=xv*w1.w;
      }
    }
    if (kc<7) wrt(buf^1);
    __syncthreads();
  }
  float4 b0 = *(const float4*)(bias2 + c0);
  float4 b1 = *(const float4*)(bias2 + c0 + 4);
  #pragma unroll
  for (int i=0;i<4;i++){
    float* dstp = out + (tok0 + r0 + i)*256 + c0;
    float4 o0, o1;
    o0.x=a0[i].x+b0.x; o0.y=a0[i].y+b0.y; o0.z=a0[i].z+b0.z; o0.w=a0[i].w+b0.w;
    o1.x=a1[i].x+b1.x; o1.y=a1[i].y+b1.y; o1.z=a1[i].z+b1.z; o1.w=a1[i].w+b1.w;
    ((float4*)dstp)[0]=o0; ((float4*)dstp)[1]=o1;
  }
}

extern "C" void kernel_launch(void* const* d_in, const int* in_sizes, int n_in,
                              void* d_out, int out_size, void* d_ws, size_t ws_size,
                              hipStream_t stream)
{
  const int*   x      = (const int*)  d_in[0];
  const float* embed  = (const float*)d_in[1];
  const float* s_ln1  = (const float*)d_in[2];
  const float* s_gw   = (const float*)d_in[3];
  const float* s_rec  = (const float*)d_in[4];
  const float* s_bias = (const float*)d_in[5];
  const float* s_gn   = (const float*)d_in[6];
  const float* s_ln2  = (const float*)d_in[7];
  const float* s_ffu  = (const float*)d_in[8];
  const float* s_ffd  = (const float*)d_in[9];
  const float* m_ln1  = (const float*)d_in[10];
  const float* m_up   = (const float*)d_in[11];
  const float* m_cw   = (const float*)d_in[12];
  const float* m_cb   = (const float*)d_in[13];
  const float* m_qkv  = (const float*)d_in[14];
  const float* m_igw  = (const float*)d_in[15];
  const float* m_igb  = (const float*)d_in[16];
  const float* m_fgw  = (const float*)d_in[17];
  const float* m_fgb  = (const float*)d_in[18];
  const float* m_skip = (const float*)d_in[19];
  const float* m_onw  = (const float*)d_in[20];
  const float* m_down = (const float*)d_in[21];
  const float* m_ln2  = (const float*)d_in[22];
  const float* m_ffu  = (const float*)d_in[23];
  const float* m_ffd  = (const float*)d_in[24];
  const float* postln = (const float*)d_in[25];
  const float* headw  = (const float*)d_in[26];
  const float* headb  = (const float*)d_in[27];

  float* p = (float*)d_ws;
  float* hbuf = p; p += 4194304;                     // (B*S*D)
  size_t avail = ws_size / 4;
  const size_t need_full = 4194304ULL + 3ULL*8388608ULL + 2ULL*131072ULL + 8192ULL;
  float* xmbuf;
  if (avail >= need_full){ xmbuf = p; p += 8388608; }
  else                   { xmbuf = (float*)d_out; }  // alias xm/h_ln into d_out if ws is small
  float* zbuf  = p; p += 8388608;
  float* xcbuf = p; p += 8388608;
  float* igbuf = p; p += 131072;
  float* fgbuf = p; p += 131072;
  float* wtab  = p; p += 8192;                       // [2][4][256][4] folded gate weights

  k_prep<<<1, 512, 0, stream>>>(m_qkv, m_igw, m_fgw, wtab);
  k_embed<<<4096, 256, 0, stream>>>(x, embed, hbuf);

  for (int i=0;i<2;i++){
    k_slstm<<<512, 512, 0, stream>>>(hbuf, s_ln1+i*128, s_gw+i*16384, s_rec+i*16384,
                                     s_bias+i*512, s_gn+i*128);
    k_ffn<<<1024, 256, 0, stream>>>(hbuf, s_ln2+i*128, s_ffu+i*32768, s_ffd+i*16384);
    k_up<<<2048, 256, 0, stream>>>(hbuf, m_ln1+i*128, m_up+i*65536, xmbuf, zbuf);
    k_convgates<<<512, 256, 0, stream>>>(xmbuf, xcbuf, m_cw+i*1024, m_cb+i*256,
                                         wtab+i*4096, m_igb+i*4, m_fgb+i*4,
                                         igbuf, fgbuf);
    k_attn<<<2048, 256, 0, stream>>>(xmbuf, xcbuf, m_qkv+i*3072, igbuf, fgbuf, m_onw+i*256);
    k_comb_down<<<1024, 256, 0, stream>>>(hbuf, xmbuf, xcbuf, zbuf, m_skip+i*256, m_down+i*32768);
    k_ffn<<<1024, 256, 0, stream>>>(hbuf, m_ln2+i*128, m_ffu+i*32768, m_ffd+i*16384);
  }

  k_head<<<1024, 256, 0, stream>>>(hbuf, postln, headw, headb, (float*)d_out);
}

// Round 8
// 1166.674 us; speedup vs baseline: 2.1132x; 1.1560x over previous
//
#include <hip/hip_runtime.h>
#include <math.h>

// B=512 S=64 D=128 V=256 NH=4 HD=32 INNER=256 NHM=4 DHM=64 BS=4 NB=64 K=4 FF=128

__device__ __forceinline__ float sigf(float x){ return 1.f/(1.f+__expf(-x)); }
__device__ __forceinline__ float siluf(float x){ return x/(1.f+__expf(-x)); }
__device__ __forceinline__ float logsigf(float x){ return fminf(x,0.f) - log1pf(__expf(-fabsf(x))); }
__device__ __forceinline__ float geluf(float x){
  return 0.5f*x*(1.f+tanhf(0.7978845608028654f*(x+0.044715f*x*x*x)));
}
__device__ __forceinline__ void sums4(float4 v, float& s, float& q){
  s += v.x+v.y+v.z+v.w;
  q += v.x*v.x+v.y*v.y+v.z*v.z+v.w*v.w;
}

// LayerNorm rows of 128; 8 threads per row; dst[r*dstride+c] = (x-mu)*rsqrt(var+eps)*w[c]
__device__ __forceinline__ void ln_rows(const float* __restrict__ src, const float* __restrict__ lnw,
                                        float* __restrict__ dst, int dstride,
                                        float (*red)[8], float (*red2)[8], int t)
{
  int r = t >> 3, l8 = t & 7;
  const float4* s4 = (const float4*)(src + (size_t)r*128 + l8*16);
  float4 v0=s4[0], v1=s4[1], v2=s4[2], v3=s4[3];
  float su=0.f, sq=0.f;
  sums4(v0,su,sq); sums4(v1,su,sq); sums4(v2,su,sq); sums4(v3,su,sq);
  red[r][l8]=su; red2[r][l8]=sq;
  __syncthreads();
  float ts=0.f, tq=0.f;
  #pragma unroll
  for (int k=0;k<8;k++){ ts+=red[r][k]; tq+=red2[r][k]; }
  float mu = ts*(1.f/128.f);
  float var = tq*(1.f/128.f) - mu*mu;
  float iv = rsqrtf(var+1e-5f);
  int c0 = l8*16;
  float vv[16];
  *(float4*)&vv[0]=v0; *(float4*)&vv[4]=v1; *(float4*)&vv[8]=v2; *(float4*)&vv[12]=v3;
  #pragma unroll
  for (int q2=0;q2<16;q2++) dst[r*dstride + c0 + q2] = (vv[q2]-mu)*iv*lnw[c0+q2];
}

// ---------------- embed ----------------
__global__ __launch_bounds__(256) void k_embed(const int* __restrict__ x, const float* __restrict__ embed,
                                               float* __restrict__ h)
{
  int idx4 = blockIdx.x*256 + threadIdx.x;      // over B*S*D/4 = 1048576 float4
  int tok = idx4 >> 5;
  int c4  = idx4 & 31;
  int id = x[tok];
  reinterpret_cast<float4*>(h)[idx4] = reinterpret_cast<const float4*>(embed)[id*32 + c4];
}

// ---------------- fold qkv blockdiag into gate weights: wtab[l][4][256][4] ----------------
// tab 0: ig from xc, 1: ig from xm, 2: fg from xc, 3: fg from xm
__global__ __launch_bounds__(512) void k_prep(
    const float* __restrict__ qkvw,  // [2][3][64][4][4]
    const float* __restrict__ igw,   // [2][768][4]
    const float* __restrict__ fgw,   // [2][768][4]
    float* __restrict__ wtab)        // [2][4][256][4]
{
  int t = threadIdx.x;               // 512
  int l = t >> 8, c = t & 255;
  int nb = c >> 2, i = c & 3;
  const float* qk  = qkvw + l*3072;
  const float* igl = igw + l*3072;
  const float* fgl = fgw + l*3072;
  float igc[4]={0,0,0,0}, igm[4]={0,0,0,0}, fgc[4]={0,0,0,0}, fgm[4]={0,0,0,0};
  #pragma unroll
  for (int o=0;o<4;o++){
    float wq = qk[nb*16 + o*4 + i];
    float wk = qk[1024 + nb*16 + o*4 + i];
    float wv = qk[2048 + nb*16 + o*4 + i];
    int no = nb*4+o;
    #pragma unroll
    for (int m=0;m<4;m++){
      igc[m] += wq*igl[no*4+m] + wk*igl[(256+no)*4+m];
      igm[m] += wv*igl[(512+no)*4+m];
      fgc[m] += wq*fgl[no*4+m] + wk*fgl[(256+no)*4+m];
      fgm[m] += wv*fgl[(512+no)*4+m];
    }
  }
  float* dst = wtab + l*4096;
  #pragma unroll
  for (int m=0;m<4;m++){
    dst[(0*256+c)*4+m] = igc[m];
    dst[(1*256+c)*4+m] = igm[m];
    dst[(2*256+c)*4+m] = fgc[m];
    dst[(3*256+c)*4+m] = fgm[m];
  }
}

// ---------------- sLSTM (fused LN + scan + head-LN + residual) ----------------
__global__ __launch_bounds__(512) void k_slstm(
    float* __restrict__ h, const float* __restrict__ lnw,
    const float* __restrict__ gw, const float* __restrict__ rw,
    const float* __restrict__ bias, const float* __restrict__ gn)
{
  __shared__ float xh[64][128];     // LN-ed input, overwritten per-step with y
  __shared__ float hb[128];
  __shared__ float raw[512];
  __shared__ float red[64][8];
  __shared__ float red2[64][8];
  __shared__ float mu_s[64][4];
  __shared__ float iv_s[64][4];

  int t = threadIdx.x;
  int b = blockIdx.x;
  float* hrow = h + (size_t)b*8192;

  ln_rows(hrow, lnw, &xh[0][0], 128, red, red2, t);
  __syncthreads();

  int g  = t >> 7;
  int nh = (t >> 5) & 3;
  int e  = t & 31;
  float wg[32], wr[32];
  {
    const float4* g4 = (const float4*)(gw + (((g*4+nh)*32+e)*32));
    const float4* r4 = (const float4*)(rw + (((g*4+nh)*32+e)*32));
    #pragma unroll
    for (int q=0;q<8;q++){
      float4 a=g4[q]; wg[4*q]=a.x; wg[4*q+1]=a.y; wg[4*q+2]=a.z; wg[4*q+3]=a.w;
      float4 c=r4[q]; wr[4*q]=c.x; wr[4*q+1]=c.y; wr[4*q+2]=c.z; wr[4*q+3]=c.w;
    }
  }
  float bs = bias[(g*4+nh)*32+e];
  float c_s=0.f, n_s=0.f, m_s=0.f;
  if (t<128) hb[t]=0.f;
  __syncthreads();

  for (int s=0;s<64;s++){
    const float4* xr = (const float4*)&xh[s][nh*32];
    const float4* hr = (const float4*)&hb[nh*32];
    float acc = bs;
    #pragma unroll
    for (int q=0;q<8;q++){
      float4 xv = xr[q]; float4 hv = hr[q];
      acc += xv.x*wg[4*q+0] + xv.y*wg[4*q+1] + xv.z*wg[4*q+2] + xv.w*wg[4*q+3];
      acc += hv.x*wr[4*q+0] + hv.y*wr[4*q+1] + hv.z*wr[4*q+2] + hv.w*wr[4*q+3];
    }
    raw[t] = acc;
    __syncthreads();
    if (t < 128){
      float i_r = raw[t], f_r = raw[128+t], z_r = raw[256+t], o_r = raw[384+t];
      float lf = m_s + logsigf(f_r);
      float mn = fmaxf(i_r, lf);
      float iv = __expf(i_r-mn), fv = __expf(lf-mn);
      c_s = fv*c_s + iv*tanhf(z_r);
      n_s = fv*n_s + iv;
      m_s = mn;
      float hn = sigf(o_r)*c_s/n_s;
      hb[t] = hn;
      xh[s][t] = hn;
    }
    __syncthreads();
  }

  if (t < 256){
    int s = t>>2, n = t&3;
    const float4* yr = (const float4*)&xh[s][n*32];
    float su=0.f, sq=0.f;
    #pragma unroll
    for (int q=0;q<8;q++){ float4 v = yr[q]; sums4(v,su,sq); }
    float mu = su*(1.f/32.f);
    float var = sq*(1.f/32.f) - mu*mu;
    mu_s[s][n]=mu; iv_s[s][n]=rsqrtf(var+1e-5f);
  }
  __syncthreads();
  #pragma unroll
  for (int rr=0; rr<16; rr++){
    int idx = t + 512*rr;
    int s = idx>>7, c = idx&127;
    float y = (xh[s][c] - mu_s[s][c>>5]) * iv_s[s][c>>5] * gn[c];
    hrow[idx] += y;
  }
}

// ---------------- FFN (fused LN + up/gelu-gate + down + residual), LDS-staged weights ----------------
// 32 tokens/block, grid = 1024
__global__ __launch_bounds__(256) void k_ffn(
    float* __restrict__ h, const float* __restrict__ lnw,
    const float* __restrict__ up, const float* __restrict__ down)
{
  __shared__ float xln[32][132];
  __shared__ float hid[32][132];
  __shared__ float bws[2][16][256];
  __shared__ float red[32][8];
  __shared__ float red2[32][8];
  int t = threadIdx.x;
  size_t tok0 = (size_t)blockIdx.x * 32;

  ln_rows(h + tok0*128, lnw, &xln[0][0], 132, red, red2, t);
  __syncthreads();

  int r0 = (t >> 5) * 4;      // 4 rows
  int c0 = (t & 31) * 4;      // 4 cols (of 128)

  // ---- GEMM1: xln(32x128) @ up(128x256) -> gelu(g)*u -> hid(32x128)
  {
    float4 regs[4];
    auto stage = [&](int kc){
      #pragma unroll
      for (int j=0;j<4;j++){
        int idx = t + 256*j;
        int row = idx >> 6, c4 = idx & 63;
        regs[j] = *(const float4*)(up + (size_t)(kc*16+row)*256 + c4*4);
      }
    };
    auto wrt = [&](int buf){
      #pragma unroll
      for (int j=0;j<4;j++){
        int idx = t + 256*j;
        int row = idx >> 6, c4 = idx & 63;
        *(float4*)&bws[buf][row][c4*4] = regs[j];
      }
    };
    stage(0); wrt(0);
    __syncthreads();
    float4 ag[4], au[4];
    #pragma unroll
    for (int i=0;i<4;i++){ ag[i]=make_float4(0,0,0,0); au[i]=make_float4(0,0,0,0); }
    for (int kc=0;kc<8;kc++){
      if (kc<7) stage(kc+1);
      int buf = kc & 1;
      #pragma unroll
      for (int k=0;k<16;k++){
        float4 wg = *(float4*)&bws[buf][k][c0];
        float4 wu = *(float4*)&bws[buf][k][c0+128];
        int kk = kc*16 + k;
        #pragma unroll
        for (int i=0;i<4;i++){
          float xv = xln[r0+i][kk];
          ag[i].x+=xv*wg.x; ag[i].y+=xv*wg.y; ag[i].z+=xv*wg.z; ag[i].w+=xv*wg.w;
          au[i].x+=xv*wu.x; au[i].y+=xv*wu.y; au[i].z+=xv*wu.z; au[i].w+=xv*wu.w;
        }
      }
      if (kc<7) wrt(buf^1);
      __syncthreads();
    }
    #pragma unroll
    for (int i=0;i<4;i++){
      hid[r0+i][c0+0] = geluf(ag[i].x)*au[i].x;
      hid[r0+i][c0+1] = geluf(ag[i].y)*au[i].y;
      hid[r0+i][c0+2] = geluf(ag[i].z)*au[i].z;
      hid[r0+i][c0+3] = geluf(ag[i].w)*au[i].w;
    }
  }
  __syncthreads();

  // ---- GEMM2: hid(32x128) @ down(128x128) -> += h
  {
    float (*bw2)[16][128] = (float (*)[16][128])bws;
    float4 regs[2];
    auto stage = [&](int kc){
      #pragma unroll
      for (int j=0;j<2;j++){
        int idx = t + 256*j;
        int row = idx >> 5, c4 = idx & 31;
        regs[j] = *(const float4*)(down + (size_t)(kc*16+row)*128 + c4*4);
      }
    };
    auto wrt = [&](int buf){
      #pragma unroll
      for (int j=0;j<2;j++){
        int idx = t + 256*j;
        int row = idx >> 5, c4 = idx & 31;
        *(float4*)&bw2[buf][row][c4*4] = regs[j];
      }
    };
    stage(0); wrt(0);
    __syncthreads();
    float4 a2[4];
    #pragma unroll
    for (int i=0;i<4;i++) a2[i]=make_float4(0,0,0,0);
    for (int kc=0;kc<8;kc++){
      if (kc<7) stage(kc+1);
      int buf = kc & 1;
      #pragma unroll
      for (int k=0;k<16;k++){
        float4 wv = *(float4*)&bw2[buf][k][c0];
        int kk = kc*16 + k;
        #pragma unroll
        for (int i=0;i<4;i++){
          float xv = hid[r0+i][kk];
          a2[i].x+=xv*wv.x; a2[i].y+=xv*wv.y; a2[i].z+=xv*wv.z; a2[i].w+=xv*wv.w;
        }
      }
      if (kc<7) wrt(buf^1);
      __syncthreads();
    }
    #pragma unroll
    for (int i=0;i<4;i++){
      float* dstp = h + (tok0 + r0 + i)*128 + c0;
      float4 hv = *(float4*)dstp;
      hv.x += a2[i].x; hv.y += a2[i].y; hv.z += a2[i].z; hv.w += a2[i].w;
      *(float4*)dstp = hv;
    }
  }
}

// ---------------- mLSTM up-projection (LN + 128->512), LDS-staged weights ----------------
// 64 tokens x 128 cols per block; grid = 512*4
__global__ __launch_bounds__(256) void k_up(
    const float* __restrict__ h, const float* __restrict__ lnw,
    const float* __restrict__ up, float* __restrict__ xm, float* __restrict__ z)
{
  __shared__ float xln[64][132];
  __shared__ float bw[2][32][128];
  __shared__ float red[64][4];
  __shared__ float red2[64][4];
  int t = threadIdx.x;
  int mt = blockIdx.x >> 2, nt = blockIdx.x & 3;
  size_t tok0 = (size_t)mt * 64;
  int n0 = nt * 128;

  // LN: 64 rows, 4 threads/row (32 cols each)
  {
    int r = t >> 2, l = t & 3;
    const float4* s4 = (const float4*)(h + (tok0 + (size_t)r)*128 + l*32);
    float4 v[8];
    float su=0.f, sq=0.f;
    #pragma unroll
    for (int q=0;q<8;q++){ v[q]=s4[q]; sums4(v[q],su,sq); }
    red[r][l]=su; red2[r][l]=sq;
    __syncthreads();
    float ts=red[r][0]+red[r][1]+red[r][2]+red[r][3];
    float tq=red2[r][0]+red2[r][1]+red2[r][2]+red2[r][3];
    float mu=ts*(1.f/128.f);
    float var=tq*(1.f/128.f)-mu*mu;
    float iv=rsqrtf(var+1e-5f);
    int cb=l*32;
    #pragma unroll
    for (int q=0;q<8;q++){
      xln[r][cb+q*4+0]=(v[q].x-mu)*iv*lnw[cb+q*4+0];
      xln[r][cb+q*4+1]=(v[q].y-mu)*iv*lnw[cb+q*4+1];
      xln[r][cb+q*4+2]=(v[q].z-mu)*iv*lnw[cb+q*4+2];
      xln[r][cb+q*4+3]=(v[q].w-mu)*iv*lnw[cb+q*4+3];
    }
  }

  float4 regs[4];
  auto stage = [&](int kc){
    #pragma unroll
    for (int j=0;j<4;j++){
      int idx = t + 256*j;
      int row = idx >> 5, c4 = idx & 31;
      regs[j] = *(const float4*)(up + (size_t)(kc*32+row)*512 + n0 + c4*4);
    }
  };
  auto wrt = [&](int buf){
    #pragma unroll
    for (int j=0;j<4;j++){
      int idx = t + 256*j;
      int row = idx >> 5, c4 = idx & 31;
      *(float4*)&bw[buf][row][c4*4] = regs[j];
    }
  };
  stage(0); wrt(0);
  __syncthreads();

  int r0 = (t >> 5) * 8;      // 8 rows
  int c0 = (t & 31) * 4;      // 4 cols (of 128)
  float4 acc4[8];
  #pragma unroll
  for (int i=0;i<8;i++) acc4[i]=make_float4(0,0,0,0);

  for (int kc=0;kc<4;kc++){
    if (kc<3) stage(kc+1);
    int buf = kc & 1;
    #pragma unroll 8
    for (int k=0;k<32;k++){
      float4 wv = *(float4*)&bw[buf][k][c0];
      int kk = kc*32 + k;
      #pragma unroll
      for (int i=0;i<8;i++){
        float xv = xln[r0+i][kk];
        acc4[i].x += xv*wv.x; acc4[i].y += xv*wv.y; acc4[i].z += xv*wv.z; acc4[i].w += xv*wv.w;
      }
    }
    if (kc<3) wrt(buf^1);
    __syncthreads();
  }

  float* dst; int cbase;
  if (n0 < 256){ dst = xm; cbase = n0 + c0; }
  else         { dst = z;  cbase = n0 - 256 + c0; }
  #pragma unroll
  for (int i=0;i<8;i++)
    *(float4*)(dst + (tok0 + r0 + i)*256 + cbase) = acc4[i];
}

// ---------------- mLSTM conv + silu + folded gate projections (no LDS) ----------------
// one block per b, 256 threads: (sr 0..3) x (c4 0..63); rolling conv window in regs
__global__ __launch_bounds__(256) void k_convgates(
    const float* __restrict__ xm, float* __restrict__ xc,
    const float* __restrict__ cw, const float* __restrict__ cb,
    const float* __restrict__ wtab,
    const float* __restrict__ igb, const float* __restrict__ fgb,
    float* __restrict__ ig, float* __restrict__ fg)
{
  int t = threadIdx.x;
  int b = blockIdx.x;
  int c4 = t & 63, sr = t >> 6;
  int c0 = c4*4;
  const float* src = xm + (size_t)b*16384;
  float* dstc = xc + (size_t)b*16384;

  // conv weights for my 4 channels (cw is [256][4], transpose into per-tap float4)
  float4 r0 = *(const float4*)(cw + (c0+0)*4);
  float4 r1 = *(const float4*)(cw + (c0+1)*4);
  float4 r2 = *(const float4*)(cw + (c0+2)*4);
  float4 r3 = *(const float4*)(cw + (c0+3)*4);
  float4 wk0 = make_float4(r0.x, r1.x, r2.x, r3.x);
  float4 wk1 = make_float4(r0.y, r1.y, r2.y, r3.y);
  float4 wk2 = make_float4(r0.z, r1.z, r2.z, r3.z);
  float4 wk3 = make_float4(r0.w, r1.w, r2.w, r3.w);
  float4 bias4 = *(const float4*)(cb + c0);

  // folded gate tables for my 4 channels
  float4 Wigc[4], Wigm[4], Wfgc[4], Wfgm[4];
  #pragma unroll
  for (int i=0;i<4;i++){
    Wigc[i] = *(const float4*)(wtab + (0*256+c0+i)*4);
    Wigm[i] = *(const float4*)(wtab + (1*256+c0+i)*4);
    Wfgc[i] = *(const float4*)(wtab + (2*256+c0+i)*4);
    Wfgm[i] = *(const float4*)(wtab + (3*256+c0+i)*4);
  }

  int s0 = sr*16;
  float4 w0 = make_float4(0,0,0,0), w1 = w0, w2 = w0;
  if (s0 >= 3){
    w0 = *(const float4*)(src + (size_t)(s0-3)*256 + c0);
    w1 = *(const float4*)(src + (size_t)(s0-2)*256 + c0);
    w2 = *(const float4*)(src + (size_t)(s0-1)*256 + c0);
  }

  for (int j=0;j<16;j++){
    int s = s0 + j;
    float4 w3 = *(const float4*)(src + (size_t)s*256 + c0);
    float4 a;
    a.x = bias4.x + w0.x*wk0.x + w1.x*wk1.x + w2.x*wk2.x + w3.x*wk3.x;
    a.y = bias4.y + w0.y*wk0.y + w1.y*wk1.y + w2.y*wk2.y + w3.y*wk3.y;
    a.z = bias4.z + w0.z*wk0.z + w1.z*wk1.z + w2.z*wk2.z + w3.z*wk3.z;
    a.w = bias4.w + w0.w*wk0.w + w1.w*wk1.w + w2.w*wk2.w + w3.w*wk3.w;
    a.x = siluf(a.x); a.y = siluf(a.y); a.z = siluf(a.z); a.w = siluf(a.w);
    *(float4*)(dstc + (size_t)s*256 + c0) = a;

    float pig[4] = {0.f,0.f,0.f,0.f};
    float pfg[4] = {0.f,0.f,0.f,0.f};
    const float xcv[4] = {a.x,a.y,a.z,a.w};
    const float xmv[4] = {w3.x,w3.y,w3.z,w3.w};
    #pragma unroll
    for (int i=0;i<4;i++){
      pig[0] += xcv[i]*Wigc[i].x + xmv[i]*Wigm[i].x;
      pig[1] += xcv[i]*Wigc[i].y + xmv[i]*Wigm[i].y;
      pig[2] += xcv[i]*Wigc[i].z + xmv[i]*Wigm[i].z;
      pig[3] += xcv[i]*Wigc[i].w + xmv[i]*Wigm[i].w;
      pfg[0] += xcv[i]*Wfgc[i].x + xmv[i]*Wfgm[i].x;
      pfg[1] += xcv[i]*Wfgc[i].y + xmv[i]*Wfgm[i].y;
      pfg[2] += xcv[i]*Wfgc[i].z + xmv[i]*Wfgm[i].z;
      pfg[3] += xcv[i]*Wfgc[i].w + xmv[i]*Wfgm[i].w;
    }
    #pragma unroll
    for (int off=32; off>=1; off>>=1){
      #pragma unroll
      for (int m=0;m<4;m++){
        pig[m] += __shfl_xor(pig[m], off, 64);
        pfg[m] += __shfl_xor(pfg[m], off, 64);
      }
    }
    if (c4 == 0){
      #pragma unroll
      for (int m=0;m<4;m++){
        ig[(size_t)b*256 + m*64 + s] = pig[m] + igb[m];
        fg[(size_t)b*256 + m*64 + s] = pfg[m] + fgb[m];
      }
    }
    w0=w1; w1=w2; w2=w3;
  }
}

// ---------------- mLSTM attention per (b, head); writes head-LN'ed h into xm buffer ----------------
// no x staging: q/k/v computed from global float4 loads with weights in regs; 71KB LDS -> 2 blocks/CU
__global__ __launch_bounds__(256) void k_attn(
    float* __restrict__ xm, const float* __restrict__ xc,
    const float* __restrict__ qkvw,
    const float* __restrict__ igp, const float* __restrict__ fgp,
    const float* __restrict__ onorm)
{
  __shared__ float qs[64][68];
  __shared__ float ksm[64][68];
  __shared__ float vsm[64][68];
  __shared__ float cnm[64][65];
  __shared__ float csum[65];
  __shared__ float pmax[64];
  __shared__ float igl[64];
  __shared__ float lfs[64];
  __shared__ float nrec[64];

  int t = threadIdx.x;
  int b = blockIdx.x >> 2, hh = blockIdx.x & 3;
  const float* xcb = xc + (size_t)b*16384 + hh*64;
  float* xmb = xm + (size_t)b*16384 + hh*64;

  if (t < 64){
    lfs[t] = logsigf(fgp[(size_t)b*256 + hh*64 + t]);
    igl[t] = igp[(size_t)b*256 + hh*64 + t];
  }
  __syncthreads();

  // qkv block weights for my lb (lb invariant across row iterations)
  int lb = t & 15;
  int nb = hh*16 + lb;
  float4 wq[4], wk[4], wv[4];
  #pragma unroll
  for (int o=0;o<4;o++){
    wq[o] = *(const float4*)(qkvw + nb*16 + o*4);
    wk[o] = *(const float4*)(qkvw + 1024 + nb*16 + o*4);
    wv[o] = *(const float4*)(qkvw + 2048 + nb*16 + o*4);
  }

  if (t == 0){
    float cacc = 0.f, pm = -1e30f;
    csum[0] = 0.f;
    for (int s=0;s<64;s++){
      cacc += lfs[s];
      csum[s+1] = cacc;
      pm = fmaxf(pm, igl[s] - cacc);
      pmax[s] = pm;
    }
  }

  #pragma unroll
  for (int j=0;j<4;j++){
    int s = (t >> 4) + j*16;
    float4 x4 = *(const float4*)(xcb + (size_t)s*256 + lb*4);
    float4 m4 = *(const float4*)(xmb + (size_t)s*256 + lb*4);
    float4 qv, kv, vv;
    qv.x = wq[0].x*x4.x + wq[0].y*x4.y + wq[0].z*x4.z + wq[0].w*x4.w;
    qv.y = wq[1].x*x4.x + wq[1].y*x4.y + wq[1].z*x4.z + wq[1].w*x4.w;
    qv.z = wq[2].x*x4.x + wq[2].y*x4.y + wq[2].z*x4.z + wq[2].w*x4.w;
    qv.w = wq[3].x*x4.x + wq[3].y*x4.y + wq[3].z*x4.z + wq[3].w*x4.w;
    kv.x = wk[0].x*x4.x + wk[0].y*x4.y + wk[0].z*x4.z + wk[0].w*x4.w;
    kv.y = wk[1].x*x4.x + wk[1].y*x4.y + wk[1].z*x4.z + wk[1].w*x4.w;
    kv.z = wk[2].x*x4.x + wk[2].y*x4.y + wk[2].z*x4.z + wk[2].w*x4.w;
    kv.w = wk[3].x*x4.x + wk[3].y*x4.y + wk[3].z*x4.z + wk[3].w*x4.w;
    vv.x = wv[0].x*m4.x + wv[0].y*m4.y + wv[0].z*m4.z + wv[0].w*m4.w;
    vv.y = wv[1].x*m4.x + wv[1].y*m4.y + wv[1].z*m4.z + wv[1].w*m4.w;
    vv.z = wv[2].x*m4.x + wv[2].y*m4.y + wv[2].z*m4.z + wv[2].w*m4.w;
    vv.w = wv[3].x*m4.x + wv[3].y*m4.y + wv[3].z*m4.z + wv[3].w*m4.w;
    *(float4*)&qs[s][lb*4]  = qv;
    *(float4*)&ksm[s][lb*4] = kv;
    *(float4*)&vsm[s][lb*4] = vv;
  }
  __syncthreads();

  int i = t >> 2;
  int jq = t & 3;
  float mi = csum[i+1] + pmax[i];

  // cache q row in registers
  float4 ql[16];
  #pragma unroll
  for (int kk=0;kk<16;kk++) ql[kk] = *(float4*)&qs[i][kk*4];

  // strided j for intra-group balance; wave-level loop clamp
  int iwmax = ((t & ~63) >> 2) + 15;       // max i in my wave
  float rs = 0.f;
  for (int jj=0; jq + jj*4 <= iwmax && jj < 16; jj++){
    int j = jq + jj*4;
    if (j <= i){
      const float4* ka = (const float4*)&ksm[j][0];
      float dp = 0.f;
      #pragma unroll
      for (int kk=0;kk<16;kk++){
        float4 a = ql[kk], c = ka[kk];
        dp += a.x*c.x + a.y*c.y + a.z*c.z + a.w*c.w;
      }
      float val = dp * 0.125f * __expf(csum[i+1] - csum[j+1] + igl[j] - mi);
      cnm[i][j] = val;
      rs += val;
    }
  }
  rs += __shfl_xor(rs, 1, 4);
  rs += __shfl_xor(rs, 2, 4);
  if (jq == 0){
    float nm = fmaxf(fabsf(rs), __expf(-mi));
    nrec[i] = 1.f/(nm + 1e-6f);
  }
  __syncthreads();

  int d0 = jq*16;
  float acc[16];
  #pragma unroll
  for (int q=0;q<16;q++) acc[q]=0.f;
  float nr = nrec[i];
  for (int j=0;j<=i;j++){
    float cwv = cnm[i][j] * nr;
    const float4* va = (const float4*)&vsm[j][d0];
    #pragma unroll
    for (int q=0;q<4;q++){
      float4 v4 = va[q];
      acc[q*4+0] += cwv*v4.x; acc[q*4+1] += cwv*v4.y; acc[q*4+2] += cwv*v4.z; acc[q*4+3] += cwv*v4.w;
    }
  }
  float su=0.f, sq=0.f;
  #pragma unroll
  for (int q=0;q<16;q++){ su += acc[q]; sq += acc[q]*acc[q]; }
  su += __shfl_xor(su,1,4); su += __shfl_xor(su,2,4);
  sq += __shfl_xor(sq,1,4); sq += __shfl_xor(sq,2,4);
  float mu = su*(1.f/64.f);
  float var = sq*(1.f/64.f) - mu*mu;
  float ivr = rsqrtf(var + 1e-5f);
  const float* onw = onorm + hh*64 + d0;
  #pragma unroll
  for (int q=0;q<4;q++){
    float4 o4;
    o4.x = (acc[q*4+0]-mu)*ivr*onw[q*4+0];
    o4.y = (acc[q*4+1]-mu)*ivr*onw[q*4+1];
    o4.z = (acc[q*4+2]-mu)*ivr*onw[q*4+2];
    o4.w = (acc[q*4+3]-mu)*ivr*onw[q*4+3];
    *(float4*)(xmb + (size_t)i*256 + d0 + q*4) = o4;
  }
}

// ---------------- mLSTM combine + down-projection + residual, LDS-staged weights ----------------
// 32 tokens/block, grid = 1024
__global__ __launch_bounds__(256) void k_comb_down(
    float* __restrict__ h, const float* __restrict__ hln,
    const float* __restrict__ xc, const float* __restrict__ z,
    const float* __restrict__ skip, const float* __restrict__ down)
{
  __shared__ float comb[32][260];
  __shared__ float bw[2][16][128];
  int t = threadIdx.x;
  size_t tok0 = (size_t)blockIdx.x*32;
  #pragma unroll
  for (int j=0;j<8;j++){
    int f4 = t + 256*j;
    int r = f4 >> 6, c4 = f4 & 63;
    size_t gi = (tok0 + r)*256 + c4*4;
    float4 a  = *(const float4*)(hln + gi);
    float4 xv = *(const float4*)(xc + gi);
    float4 zv = *(const float4*)(z + gi);
    float4 sk = *(const float4*)(skip + c4*4);
    float4 o;
    o.x = (a.x + sk.x*xv.x)*siluf(zv.x);
    o.y = (a.y + sk.y*xv.y)*siluf(zv.y);
    o.z = (a.z + sk.z*xv.z)*siluf(zv.z);
    o.w = (a.w + sk.w*xv.w)*siluf(zv.w);
    *(float4*)&comb[r][c4*4] = o;
  }

  float4 regs[2];
  auto stage = [&](int kc){
    #pragma unroll
    for (int j=0;j<2;j++){
      int idx = t + 256*j;
      int row = idx >> 5, c4 = idx & 31;
      regs[j] = *(const float4*)(down + (size_t)(kc*16+row)*128 + c4*4);
    }
  };
  auto wrt = [&](int buf){
    #pragma unroll
    for (int j=0;j<2;j++){
      int idx = t + 256*j;
      int row = idx >> 5, c4 = idx & 31;
      *(float4*)&bw[buf][row][c4*4] = regs[j];
    }
  };
  stage(0); wrt(0);
  __syncthreads();

  int r0 = (t >> 5) * 4;
  int c0 = (t & 31) * 4;
  float4 a2[4];
  #pragma unroll
  for (int i=0;i<4;i++) a2[i]=make_float4(0,0,0,0);
  for (int kc=0;kc<16;kc++){
    if (kc<15) stage(kc+1);
    int buf = kc & 1;
    #pragma unroll
    for (int k=0;k<16;k++){
      float4 wv = *(float4*)&bw[buf][k][c0];
      int kk = kc*16 + k;
      #pragma unroll
      for (int i=0;i<4;i++){
        float xv = comb[r0+i][kk];
        a2[i].x+=xv*wv.x; a2[i].y+=xv*wv.y; a2[i].z+=xv*wv.z; a2[i].w+=xv*wv.w;
      }
    }
    if (kc<15) wrt(buf^1);
    __syncthreads();
  }
  #pragma unroll
  for (int i=0;i<4;i++){
    float* dstp = h + (tok0 + r0 + i)*128 + c0;
    float4 hv = *(float4*)dstp;
    hv.x += a2[i].x; hv.y += a2[i].y; hv.z += a2[i].z; hv.w += a2[i].w;
    *(float4*)dstp = hv;
  }
}

// ---------------- final LN + head, LDS-staged weights ----------------
// 32 tokens/block, grid = 1024
__global__ __launch_bounds__(256) void k_head(
    const float* __restrict__ h, const float* __restrict__ lnw,
    const float* __restrict__ w, const float* __restrict__ bias2,
    float* __restrict__ out)
{
  __shared__ float xln[32][132];
  __shared__ float bws[2][16][256];
  __shared__ float red[32][8];
  __shared__ float red2[32][8];
  int t = threadIdx.x;
  size_t tok0 = (size_t)blockIdx.x * 32;

  ln_rows(h + tok0*128, lnw, &xln[0][0], 132, red, red2, t);
  __syncthreads();

  float4 regs[4];
  auto stage = [&](int kc){
    #pragma unroll
    for (int j=0;j<4;j++){
      int idx = t + 256*j;
      int row = idx >> 6, c4 = idx & 63;
      regs[j] = *(const float4*)(w + (size_t)(kc*16+row)*256 + c4*4);
    }
  };
  auto wrt = [&](int buf){
    #pragma unroll
    for (int j=0;j<4;j++){
      int idx = t + 256*j;
      int row = idx >> 6, c4 = idx & 63;
      *(float4*)&bws[buf][row][c4*4] = regs[j];
    }
  };
  stage(0); wrt(0);
  __syncthreads();

  int r0 = (t >> 5) * 4;
  int c0 = (t & 31) * 8;
  float4 a0[4], a1[4];
  #pragma unroll
  for (int i=0;i<4;i++){ a0[i]=make_float4(0,0,0,0); a1[i]=make_float4(0,0,0,0); }
  for (int kc=0;kc<8;kc++){
    if (kc<7) stage(kc+1);
    int buf = kc & 1;
    #pragma unroll
    for (int k=0;k<16;k++){
      float4 w0 = *(float4*)&bws[buf][k][c0];
      float4 w1 = *(float4*)&bws[buf][k][c0+4];
      int kk = kc*16 + k;
      #pragma unroll
      for (int i=0;i<4;i++){
        float xv = xln[r0+i][kk];
        a0[i].x+=xv*w0.x; a0[i].y+=xv*w0.y; a0[i].z+=xv*w0.z; a0[i].w+=xv*w0.w;
        a1[i].x+=xv*w1.x; a1[i].y+=xv*w1.y; a1[i].z+=xv*w1.z; a1[i].w+=xv*w1.w;
      }
    }
    if (kc<7) wrt(buf^1);
    __syncthreads();
  }
  float4 b0 = *(const float4*)(bias2 + c0);
  float4 b1 = *(const float4*)(bias2 + c0 + 4);
  #pragma unroll
  for (int i=0;i<4;i++){
    float* dstp = out + (tok0 + r0 + i)*256 + c0;
    float4 o0, o1;
    o0.x=a0[i].x+b0.x; o0.y=a0[i].y+b0.y; o0.z=a0[i].z+b0.z; o0.w=a0[i].w+b0.w;
    o1.x=a1[i].x+b1.x; o1.y=a1[i].y+b1.y; o1.z=a1[i].z+b1.z; o1.w=a1[i].w+b1.w;
    ((float4*)dstp)[0]=o0; ((float4*)dstp)[1]=o1;
  }
}

extern "C" void kernel_launch(void* const* d_in, const int* in_sizes, int n_in,
                              void* d_out, int out_size, void* d_ws, size_t ws_size,
                              hipStream_t stream)
{
  const int*   x      = (const int*)  d_in[0];
  const float* embed  = (const float*)d_in[1];
  const float* s_ln1  = (const float*)d_in[2];
  const float* s_gw   = (const float*)d_in[3];
  const float* s_rec  = (const float*)d_in[4];
  const float* s_bias = (const float*)d_in[5];
  const float* s_gn   = (const float*)d_in[6];
  const float* s_ln2  = (const float*)d_in[7];
  const float* s_ffu  = (const float*)d_in[8];
  const float* s_ffd  = (const float*)d_in[9];
  const float* m_ln1  = (const float*)d_in[10];
  const float* m_up   = (const float*)d_in[11];
  const float* m_cw   = (const float*)d_in[12];
  const float* m_cb   = (const float*)d_in[13];
  const float* m_qkv  = (const float*)d_in[14];
  const float* m_igw  = (const float*)d_in[15];
  const float* m_igb  = (const float*)d_in[16];
  const float* m_fgw  = (const float*)d_in[17];
  const float* m_fgb  = (const float*)d_in[18];
  const float* m_skip = (const float*)d_in[19];
  const float* m_onw  = (const float*)d_in[20];
  const float* m_down = (const float*)d_in[21];
  const float* m_ln2  = (const float*)d_in[22];
  const float* m_ffu  = (const float*)d_in[23];
  const float* m_ffd  = (const float*)d_in[24];
  const float* postln = (const float*)d_in[25];
  const float* headw  = (const float*)d_in[26];
  const float* headb  = (const float*)d_in[27];

  float* p = (float*)d_ws;
  float* hbuf = p; p += 4194304;                     // (B*S*D)
  size_t avail = ws_size / 4;
  const size_t need_full = 4194304ULL + 3ULL*8388608ULL + 2ULL*131072ULL + 8192ULL;
  float* xmbuf;
  if (avail >= need_full){ xmbuf = p; p += 8388608; }
  else                   { xmbuf = (float*)d_out; }  // alias xm/h_ln into d_out if ws is small
  float* zbuf  = p; p += 8388608;
  float* xcbuf = p; p += 8388608;
  float* igbuf = p; p += 131072;
  float* fgbuf = p; p += 131072;
  float* wtab  = p; p += 8192;                       // [2][4][256][4] folded gate weights

  k_prep<<<1, 512, 0, stream>>>(m_qkv, m_igw, m_fgw, wtab);
  k_embed<<<4096, 256, 0, stream>>>(x, embed, hbuf);

  for (int i=0;i<2;i++){
    k_slstm<<<512, 512, 0, stream>>>(hbuf, s_ln1+i*128, s_gw+i*16384, s_rec+i*16384,
                                     s_bias+i*512, s_gn+i*128);
    k_ffn<<<1024, 256, 0, stream>>>(hbuf, s_ln2+i*128, s_ffu+i*32768, s_ffd+i*16384);
    k_up<<<2048, 256, 0, stream>>>(hbuf, m_ln1+i*128, m_up+i*65536, xmbuf, zbuf);
    k_convgates<<<512, 256, 0, stream>>>(xmbuf, xcbuf, m_cw+i*1024, m_cb+i*256,
                                         wtab+i*4096, m_igb+i*4, m_fgb+i*4,
                                         igbuf, fgbuf);
    k_attn<<<2048, 256, 0, stream>>>(xmbuf, xcbuf, m_qkv+i*3072, igbuf, fgbuf, m_onw+i*256);
    k_comb_down<<<1024, 256, 0, stream>>>(hbuf, xmbuf, xcbuf, zbuf, m_skip+i*256, m_down+i*32768);
    k_ffn<<<1024, 256, 0, stream>>>(hbuf, m_ln2+i*128, m_ffu+i*32768, m_ffd+i*16384);
  }

  k_head<<<1024, 256, 0, stream>>>(hbuf, postln, headw, headb, (float*)d_out);
}